// Round 1
// baseline (1886.385 us; speedup 1.0000x reference)
//
#include <hip/hip_runtime.h>
#include <math.h>

#define B_DIM 2
#define C_DIM 1024
#define D_DIM 64
#define N_DIM 128
#define P_DIM (D_DIM * N_DIM)   // 8192 positions per (b, c)

// ---------------------------------------------------------------------------
// Projection GEMM: Y[b,o,p] = act( sum_c W[o,c] * X[b,c,p] )
// W: [1024,1024] row-major. X,Y: [B,1024,8192].
// 128x128 tile, BK=16, 256 threads, 8x8 per-thread micro-tile.
// ---------------------------------------------------------------------------
template <bool GELU>
__global__ __launch_bounds__(256) void proj_gemm(const float* __restrict__ W,
                                                 const float* __restrict__ X,
                                                 float* __restrict__ Y)
{
    __shared__ float As[16][132];   // A transposed: As[kk][m], row=132 keeps 16B align
    __shared__ float Bs[16][132];   // Bs[kk][n]

    const int bm = blockIdx.x;   // 0..7   (M tiles)
    const int bn = blockIdx.y;   // 0..63  (N tiles)
    const int b  = blockIdx.z;   // 0..1
    const float* Xb = X + (size_t)b * C_DIM * P_DIM;
    float*       Yb = Y + (size_t)b * C_DIM * P_DIM;

    const int tid = threadIdx.x;
    const int tn  = tid & 15;    // column group (j)
    const int tm  = tid >> 4;    // row group (i)

    const int row0 = bm * 128;
    const int col0 = bn * 128;

    float acc[8][8] = {};

    for (int k0 = 0; k0 < C_DIM; k0 += 16) {
        // A tile: W[row0+m, k0+kk], 128x16 -> As[kk][m] (transposed)
        #pragma unroll
        for (int t = tid; t < 512; t += 256) {
            const int m   = t >> 2;          // 0..127
            const int kk4 = (t & 3) * 4;     // 0,4,8,12
            const float4 a = *reinterpret_cast<const float4*>(
                &W[(size_t)(row0 + m) * C_DIM + k0 + kk4]);
            As[kk4 + 0][m] = a.x;
            As[kk4 + 1][m] = a.y;
            As[kk4 + 2][m] = a.z;
            As[kk4 + 3][m] = a.w;
        }
        // B tile: X[b, k0+kk, col0+n], 16x128 -> Bs[kk][n]
        #pragma unroll
        for (int t = tid; t < 512; t += 256) {
            const int kk = t >> 5;           // 0..15
            const int n4 = (t & 31) * 4;     // 0..124
            const float4 v = *reinterpret_cast<const float4*>(
                &Xb[(size_t)(k0 + kk) * P_DIM + col0 + n4]);
            *reinterpret_cast<float4*>(&Bs[kk][n4]) = v;
        }
        __syncthreads();

        #pragma unroll
        for (int kk = 0; kk < 16; ++kk) {
            float a[8], bb[8];
            const float4 a0 = *reinterpret_cast<const float4*>(&As[kk][tm * 8]);
            const float4 a1 = *reinterpret_cast<const float4*>(&As[kk][tm * 8 + 4]);
            a[0] = a0.x; a[1] = a0.y; a[2] = a0.z; a[3] = a0.w;
            a[4] = a1.x; a[5] = a1.y; a[6] = a1.z; a[7] = a1.w;
            const float4 b0 = *reinterpret_cast<const float4*>(&Bs[kk][tn * 8]);
            const float4 b1 = *reinterpret_cast<const float4*>(&Bs[kk][tn * 8 + 4]);
            bb[0] = b0.x; bb[1] = b0.y; bb[2] = b0.z; bb[3] = b0.w;
            bb[4] = b1.x; bb[5] = b1.y; bb[6] = b1.z; bb[7] = b1.w;
            #pragma unroll
            for (int i = 0; i < 8; ++i)
                #pragma unroll
                for (int j = 0; j < 8; ++j)
                    acc[i][j] = fmaf(a[i], bb[j], acc[i][j]);
        }
        __syncthreads();
    }

    // Epilogue
    #pragma unroll
    for (int i = 0; i < 8; ++i) {
        const int o = row0 + tm * 8 + i;
        float* dst = &Yb[(size_t)o * P_DIM + col0 + tn * 8];
        float vals[8];
        #pragma unroll
        for (int j = 0; j < 8; ++j) {
            float v = acc[i][j];
            if (GELU) v = 0.5f * v * (1.0f + erff(v * 0.70710678118654752f));
            vals[j] = v;
        }
        *reinterpret_cast<float4*>(dst)     = make_float4(vals[0], vals[1], vals[2], vals[3]);
        *reinterpret_cast<float4*>(dst + 4) = make_float4(vals[4], vals[5], vals[6], vals[7]);
    }
}

// ---------------------------------------------------------------------------
// Fused attention per (b,h): S = scale*Q^T K -> row softmax -> O = V P^T
// Q,K,V: [64][128] fp32 per (b,h). One workgroup per (b,h), 256 threads.
// Output written over the q workspace buffer (disjoint per block).
// ---------------------------------------------------------------------------
#define RS 129   // S row stride (pad: lane-varying i hits distinct banks)
#define RV 132   // K/V row stride (16B aligned, 2-way-max conflicts)

__global__ __launch_bounds__(256) void attn_kernel(const float* __restrict__ q,
                                                   const float* __restrict__ k,
                                                   const float* __restrict__ v,
                                                   float* __restrict__ o)
{
    __shared__ float Qs[64 * 128];    // 32 KB
    __shared__ float KVs[64 * RV];    // 33 KB (K, then reused for V)
    __shared__ float Ss[128 * RS];    // 64.5 KB

    const int bh = blockIdx.x;   // b*C + h, 0..2047
    const float* qp = q + (size_t)bh * 64 * 128;
    const float* kp = k + (size_t)bh * 64 * 128;
    const float* vp = v + (size_t)bh * 64 * 128;
    float*       op = o + (size_t)bh * 64 * 128;
    const int tid = threadIdx.x;

    // Load Q and K into LDS (float4, coalesced)
    #pragma unroll
    for (int t = tid; t < 2048; t += 256) {
        const int d  = t >> 5;          // 0..63
        const int c4 = (t & 31) * 4;    // 0..124
        *reinterpret_cast<float4*>(&Qs[d * 128 + c4]) =
            *reinterpret_cast<const float4*>(&qp[d * 128 + c4]);
        *reinterpret_cast<float4*>(&KVs[d * RV + c4]) =
            *reinterpret_cast<const float4*>(&kp[d * 128 + c4]);
    }
    __syncthreads();

    // S[i][j] = 0.125 * sum_d Q[d][i] * K[d][j]
    {
        const int si = tid >> 4;   // i0 = si*8
        const int sj = tid & 15;   // j0 = sj*8
        float accS[8][8] = {};
        for (int d = 0; d < 64; ++d) {
            float a[8], bb[8];
            const float4 a0 = *reinterpret_cast<const float4*>(&Qs[d * 128 + si * 8]);
            const float4 a1 = *reinterpret_cast<const float4*>(&Qs[d * 128 + si * 8 + 4]);
            a[0] = a0.x; a[1] = a0.y; a[2] = a0.z; a[3] = a0.w;
            a[4] = a1.x; a[5] = a1.y; a[6] = a1.z; a[7] = a1.w;
            const float4 b0 = *reinterpret_cast<const float4*>(&KVs[d * RV + sj * 8]);
            const float4 b1 = *reinterpret_cast<const float4*>(&KVs[d * RV + sj * 8 + 4]);
            bb[0] = b0.x; bb[1] = b0.y; bb[2] = b0.z; bb[3] = b0.w;
            bb[4] = b1.x; bb[5] = b1.y; bb[6] = b1.z; bb[7] = b1.w;
            #pragma unroll
            for (int i = 0; i < 8; ++i)
                #pragma unroll
                for (int j = 0; j < 8; ++j)
                    accS[i][j] = fmaf(a[i], bb[j], accS[i][j]);
        }
        #pragma unroll
        for (int i = 0; i < 8; ++i)
            #pragma unroll
            for (int j = 0; j < 8; ++j)
                Ss[(si * 8 + i) * RS + sj * 8 + j] = accS[i][j] * 0.125f;
    }
    __syncthreads();

    // Load V over K's LDS region (K fully consumed above; overlaps softmax)
    #pragma unroll
    for (int t = tid; t < 2048; t += 256) {
        const int d  = t >> 5;
        const int c4 = (t & 31) * 4;
        *reinterpret_cast<float4*>(&KVs[d * RV + c4]) =
            *reinterpret_cast<const float4*>(&vp[d * 128 + c4]);
    }

    // Row softmax (threads 0..127, one row each; conflict-free: bank=(i+j)%32)
    if (tid < 128) {
        float m = -INFINITY;
        for (int j = 0; j < 128; ++j) m = fmaxf(m, Ss[tid * RS + j]);
        float s = 0.f;
        for (int j = 0; j < 128; ++j) {
            const float e = __expf(Ss[tid * RS + j] - m);
            Ss[tid * RS + j] = e;
            s += e;
        }
        const float inv = 1.0f / s;
        for (int j = 0; j < 128; ++j) Ss[tid * RS + j] *= inv;
    }
    __syncthreads();

    // O[d][i] = sum_j V[d][j] * P[i][j]; thread: d in {td*4..+4}, i in {ti+16*ii}
    {
        const int ti = tid & 15;
        const int td = tid >> 4;   // 0..15
        float acc[4][8] = {};
        for (int j = 0; j < 128; ++j) {
            float vv[4], ss[8];
            #pragma unroll
            for (int di = 0; di < 4; ++di) vv[di] = KVs[(td * 4 + di) * RV + j];
            #pragma unroll
            for (int ii = 0; ii < 8; ++ii) ss[ii] = Ss[(ti + 16 * ii) * RS + j];
            #pragma unroll
            for (int di = 0; di < 4; ++di)
                #pragma unroll
                for (int ii = 0; ii < 8; ++ii)
                    acc[di][ii] = fmaf(vv[di], ss[ii], acc[di][ii]);
        }
        #pragma unroll
        for (int di = 0; di < 4; ++di)
            #pragma unroll
            for (int ii = 0; ii < 8; ++ii)
                op[(td * 4 + di) * 128 + ti + 16 * ii] = acc[di][ii];
    }
}

// ---------------------------------------------------------------------------
extern "C" void kernel_launch(void* const* d_in, const int* in_sizes, int n_in,
                              void* d_out, int out_size, void* d_ws, size_t ws_size,
                              hipStream_t stream)
{
    const float* lidar = (const float*)d_in[0];
    const float* cam   = (const float*)d_in[1];
    const float* Wq    = (const float*)d_in[2];
    const float* Wk    = (const float*)d_in[3];
    const float* Wv    = (const float*)d_in[4];
    const float* Wo    = (const float*)d_in[5];
    float* out = (float*)d_out;

    const size_t tensor_elems = (size_t)B_DIM * C_DIM * P_DIM;  // 16,777,216
    float* qb = (float*)d_ws;
    float* kb = qb + tensor_elems;
    float* vb = kb + tensor_elems;

    const dim3 grid(8, 64, 2);
    const dim3 blk(256);

    proj_gemm<false><<<grid, blk, 0, stream>>>(Wq, lidar, qb);
    proj_gemm<false><<<grid, blk, 0, stream>>>(Wk, cam,   kb);
    proj_gemm<false><<<grid, blk, 0, stream>>>(Wv, cam,   vb);

    attn_kernel<<<dim3(B_DIM * C_DIM), blk, 0, stream>>>(qb, kb, vb, qb);

    proj_gemm<true><<<grid, blk, 0, stream>>>(Wo, qb, out);
}

// Round 2
// 462.696 us; speedup vs baseline: 4.0769x; 4.0769x over previous
//
#include <hip/hip_runtime.h>
#include <math.h>

#define CH  1024
#define PPB 8192            // positions per batch (D*N = 64*128)
#define NB  2

typedef __attribute__((ext_vector_type(8))) short short8;
typedef __attribute__((ext_vector_type(4))) float f32x4;

__device__ __forceinline__ ushort f2bf(float x) {
    uint u = __float_as_uint(x);
    return (ushort)((u + 0x7FFFu + ((u >> 16) & 1u)) >> 16);   // RNE
}
__device__ __forceinline__ float bf2f(ushort u) {
    return __uint_as_float(((uint)u) << 16);
}
__device__ __forceinline__ void gload16(const void* g, const void* l) {
    __builtin_amdgcn_global_load_lds((const __attribute__((address_space(1))) void*)g,
                                     (__attribute__((address_space(3))) void*)l, 16, 0, 0);
}

// ---------------------------------------------------------------------------
// Weight fp32 -> bf16 (4 x 1M elements)
// ---------------------------------------------------------------------------
__global__ __launch_bounds__(256) void conv_w4(const float* __restrict__ w0,
                                               const float* __restrict__ w1,
                                               const float* __restrict__ w2,
                                               const float* __restrict__ w3,
                                               ushort* __restrict__ dst)
{
    const int y = blockIdx.y;
    const float* w = (y == 0) ? w0 : (y == 1) ? w1 : (y == 2) ? w2 : w3;
    ushort* o = dst + (size_t)y * (1u << 20);
    const int idx = (blockIdx.x * 256 + threadIdx.x) * 8;
    const float4 v0 = *(const float4*)(w + idx);
    const float4 v1 = *(const float4*)(w + idx + 4);
    ushort4 o0, o1;
    o0.x = f2bf(v0.x); o0.y = f2bf(v0.y); o0.z = f2bf(v0.z); o0.w = f2bf(v0.w);
    o1.x = f2bf(v1.x); o1.y = f2bf(v1.y); o1.z = f2bf(v1.z); o1.w = f2bf(v1.w);
    *(ushort4*)(o + idx)     = o0;
    *(ushort4*)(o + idx + 4) = o1;
}

// ---------------------------------------------------------------------------
// Transpose + convert: in[b][c][p] (f32 or bf16) -> out[b][p][c] bf16
// 64x64 tiles, LDS float T[64][65]
// ---------------------------------------------------------------------------
template <bool IN_F32>
__global__ __launch_bounds__(256) void transpose_cvt(const void* __restrict__ in_,
                                                     ushort* __restrict__ out)
{
    __shared__ float T[64][65];
    const int p0 = blockIdx.x * 64;   // 0..127 tiles
    const int c0 = blockIdx.y * 64;   // 0..15 tiles
    const int b  = blockIdx.z;
    const int t  = threadIdx.x;
    const int rc = t >> 4;            // 0..15
    const int rp = (t & 15) * 4;      // 0..60

    #pragma unroll
    for (int pass = 0; pass < 4; ++pass) {
        const int c = pass * 16 + rc;
        const size_t base = ((size_t)(b * CH + c0 + c)) * PPB + p0 + rp;
        if (IN_F32) {
            const float4 v = *(const float4*)((const float*)in_ + base);
            T[c][rp] = v.x; T[c][rp + 1] = v.y; T[c][rp + 2] = v.z; T[c][rp + 3] = v.w;
        } else {
            const ushort4 v = *(const ushort4*)((const ushort*)in_ + base);
            T[c][rp]     = bf2f(v.x); T[c][rp + 1] = bf2f(v.y);
            T[c][rp + 2] = bf2f(v.z); T[c][rp + 3] = bf2f(v.w);
        }
    }
    __syncthreads();
    #pragma unroll
    for (int pass = 0; pass < 4; ++pass) {
        const int p = pass * 16 + rc;
        ushort4 o;
        o.x = f2bf(T[rp + 0][p]); o.y = f2bf(T[rp + 1][p]);
        o.z = f2bf(T[rp + 2][p]); o.w = f2bf(T[rp + 3][p]);
        *(ushort4*)(out + ((size_t)(b * PPB + p0 + p)) * CH + c0 + rp) = o;
    }
}

// ---------------------------------------------------------------------------
// bf16 MFMA GEMM (m97 structure): C[m][n] = sum_k A[m][k] * Bt[n][k]
// A: [1024][1024] bf16. Bt: [16384][1024] bf16. 128x128 tile, BK=32,
// 4 waves, 16x16x32 MFMA, global_load_lds(16B), double-buffered LDS.
// MODE 0: write bf16 [b][m][p]. MODE 1: write f32 gelu [b][m][p].
// ---------------------------------------------------------------------------
template <int MODE>
__global__ __launch_bounds__(256) void gemm_bt(const ushort* __restrict__ A,
                                               const ushort* __restrict__ Bt,
                                               void* __restrict__ Cout)
{
    __shared__ ushort As[2][128 * 32];
    __shared__ ushort Bs[2][128 * 32];

    const int bid = blockIdx.x;                 // 1024 blocks, 1024%8==0
    const int sid = (bid & 7) * 128 + (bid >> 3);  // XCD swizzle
    const int bm  = sid & 7;
    const int bn  = sid >> 3;                   // 0..127
    const int m0  = bm * 128;
    const int n0g = bn * 128;                   // row in Bt
    const int b   = bn >> 6;
    const int p0  = (bn & 63) * 128;

    const int tid = threadIdx.x;
    const int w   = tid >> 6;
    const int l   = tid & 63;
    const int wr  = w >> 1, wc = w & 1;

    f32x4 acc[4][4];
    #pragma unroll
    for (int i = 0; i < 4; ++i)
        #pragma unroll
        for (int j = 0; j < 4; ++j) acc[i][j] = (f32x4)(0.0f);

    auto stage = [&](int buf, int kt) {
        const int k0 = kt * 32;
        #pragma unroll
        for (int i = 0; i < 2; ++i) {
            const int c = w * 2 + i;            // chunk 0..7 (16 rows each)
            const int r = c * 16 + (l >> 2);
            const int ke = k0 + (l & 3) * 8;
            gload16(A  + (size_t)(m0  + r) * CH + ke, &As[buf][c * 512]);
            gload16(Bt + (size_t)(n0g + r) * CH + ke, &Bs[buf][c * 512]);
        }
    };

    stage(0, 0);
    int buf = 0;
    const int ks = (l >> 4) * 8;
    const int fr = l & 15;
    for (int kt = 0; kt < 32; ++kt) {
        __syncthreads();                        // drains vmcnt: buf staged
        if (kt + 1 < 32) stage(buf ^ 1, kt + 1);
        short8 af[4], bfr[4];
        #pragma unroll
        for (int fm = 0; fm < 4; ++fm)
            af[fm] = *reinterpret_cast<const short8*>(
                &As[buf][(wr * 64 + fm * 16 + fr) * 32 + ks]);
        #pragma unroll
        for (int fn = 0; fn < 4; ++fn)
            bfr[fn] = *reinterpret_cast<const short8*>(
                &Bs[buf][(wc * 64 + fn * 16 + fr) * 32 + ks]);
        #pragma unroll
        for (int fm = 0; fm < 4; ++fm)
            #pragma unroll
            for (int fn = 0; fn < 4; ++fn)
                acc[fm][fn] = __builtin_amdgcn_mfma_f32_16x16x32_bf16(
                    af[fm], bfr[fn], acc[fm][fn], 0, 0, 0);
        buf ^= 1;
    }

    // epilogue: C/D layout col=lane&15, row=(lane>>4)*4+reg (m89-verified)
    const int rq = l >> 4;
    #pragma unroll
    for (int fm = 0; fm < 4; ++fm) {
        #pragma unroll
        for (int fn = 0; fn < 4; ++fn) {
            #pragma unroll
            for (int r = 0; r < 4; ++r) {
                const int m = m0 + wr * 64 + fm * 16 + rq * 4 + r;
                const int n = wc * 64 + fn * 16 + fr;
                const float vv = acc[fm][fn][r];
                const size_t off = (size_t)b * CH * PPB + (size_t)m * PPB + p0 + n;
                if (MODE == 0) {
                    ((ushort*)Cout)[off] = f2bf(vv);
                } else {
                    ((float*)Cout)[off] = 0.5f * vv * (1.0f + erff(vv * 0.70710678118654752f));
                }
            }
        }
    }
}

// ---------------------------------------------------------------------------
// Fused attention per (b,h): bf16 in, fp32 math, bf16 out (over q buffer).
// ---------------------------------------------------------------------------
#define RS 129
#define RV 132

__global__ __launch_bounds__(256) void attn_kernel(const ushort* __restrict__ q,
                                                   const ushort* __restrict__ k,
                                                   const ushort* __restrict__ v,
                                                   ushort* __restrict__ o)
{
    __shared__ float Qs[64 * 128];
    __shared__ float KVs[64 * RV];
    __shared__ float Ss[128 * RS];

    const int bh = blockIdx.x;
    const ushort* qp = q + (size_t)bh * 8192;
    const ushort* kp = k + (size_t)bh * 8192;
    const ushort* vp = v + (size_t)bh * 8192;
    ushort*       op = o + (size_t)bh * 8192;
    const int tid = threadIdx.x;

    // Load Q and K (bf16x8 = 16B), expand to fp32 LDS
    #pragma unroll
    for (int t = tid; t < 1024; t += 256) {
        const int d  = t >> 4;
        const int c8 = (t & 15) * 8;
        const uint4 qv = *(const uint4*)(qp + (size_t)d * 128 + c8);
        const uint4 kv = *(const uint4*)(kp + (size_t)d * 128 + c8);
        const uint qa[4] = {qv.x, qv.y, qv.z, qv.w};
        const uint ka[4] = {kv.x, kv.y, kv.z, kv.w};
        float* Qd = &Qs[d * 128 + c8];
        float* Kd = &KVs[d * RV + c8];
        #pragma unroll
        for (int j = 0; j < 4; ++j) {
            Qd[2 * j]     = __uint_as_float(qa[j] << 16);
            Qd[2 * j + 1] = __uint_as_float(qa[j] & 0xFFFF0000u);
            Kd[2 * j]     = __uint_as_float(ka[j] << 16);
            Kd[2 * j + 1] = __uint_as_float(ka[j] & 0xFFFF0000u);
        }
    }
    __syncthreads();

    // S[i][j] = 0.125 * sum_d Q[d][i] * K[d][j]
    {
        const int si = tid >> 4;
        const int sj = tid & 15;
        float accS[8][8] = {};
        for (int d = 0; d < 64; ++d) {
            float a[8], bb[8];
            const float4 a0 = *(const float4*)(&Qs[d * 128 + si * 8]);
            const float4 a1 = *(const float4*)(&Qs[d * 128 + si * 8 + 4]);
            a[0] = a0.x; a[1] = a0.y; a[2] = a0.z; a[3] = a0.w;
            a[4] = a1.x; a[5] = a1.y; a[6] = a1.z; a[7] = a1.w;
            const float4 b0 = *(const float4*)(&KVs[d * RV + sj * 8]);
            const float4 b1 = *(const float4*)(&KVs[d * RV + sj * 8 + 4]);
            bb[0] = b0.x; bb[1] = b0.y; bb[2] = b0.z; bb[3] = b0.w;
            bb[4] = b1.x; bb[5] = b1.y; bb[6] = b1.z; bb[7] = b1.w;
            #pragma unroll
            for (int i = 0; i < 8; ++i)
                #pragma unroll
                for (int j = 0; j < 8; ++j)
                    accS[i][j] = fmaf(a[i], bb[j], accS[i][j]);
        }
        #pragma unroll
        for (int i = 0; i < 8; ++i)
            #pragma unroll
            for (int j = 0; j < 8; ++j)
                Ss[(si * 8 + i) * RS + sj * 8 + j] = accS[i][j] * 0.125f;
    }
    __syncthreads();

    // Load V over K region (K consumed; overlaps softmax)
    #pragma unroll
    for (int t = tid; t < 1024; t += 256) {
        const int d  = t >> 4;
        const int c8 = (t & 15) * 8;
        const uint4 vv = *(const uint4*)(vp + (size_t)d * 128 + c8);
        const uint va[4] = {vv.x, vv.y, vv.z, vv.w};
        float* Vd = &KVs[d * RV + c8];
        #pragma unroll
        for (int j = 0; j < 4; ++j) {
            Vd[2 * j]     = __uint_as_float(va[j] << 16);
            Vd[2 * j + 1] = __uint_as_float(va[j] & 0xFFFF0000u);
        }
    }

    // Row softmax (threads 0..127)
    if (tid < 128) {
        float m = -INFINITY;
        for (int j = 0; j < 128; ++j) m = fmaxf(m, Ss[tid * RS + j]);
        float s = 0.f;
        for (int j = 0; j < 128; ++j) {
            const float e = __expf(Ss[tid * RS + j] - m);
            Ss[tid * RS + j] = e;
            s += e;
        }
        const float inv = 1.0f / s;
        for (int j = 0; j < 128; ++j) Ss[tid * RS + j] *= inv;
    }
    __syncthreads();

    // O[d][i] = sum_j V[d][j] * P[i][j]
    {
        const int ti = tid & 15;
        const int td = tid >> 4;
        float acc[4][8] = {};
        for (int j = 0; j < 128; ++j) {
            float vv[4], ss[8];
            #pragma unroll
            for (int di = 0; di < 4; ++di) vv[di] = KVs[(td * 4 + di) * RV + j];
            #pragma unroll
            for (int ii = 0; ii < 8; ++ii) ss[ii] = Ss[(ti + 16 * ii) * RS + j];
            #pragma unroll
            for (int di = 0; di < 4; ++di)
                #pragma unroll
                for (int ii = 0; ii < 8; ++ii)
                    acc[di][ii] = fmaf(vv[di], ss[ii], acc[di][ii]);
        }
        #pragma unroll
        for (int di = 0; di < 4; ++di)
            #pragma unroll
            for (int ii = 0; ii < 8; ++ii)
                op[(td * 4 + di) * 128 + ti + 16 * ii] = f2bf(acc[di][ii]);
    }
}

// ---------------------------------------------------------------------------
extern "C" void kernel_launch(void* const* d_in, const int* in_sizes, int n_in,
                              void* d_out, int out_size, void* d_ws, size_t ws_size,
                              hipStream_t stream)
{
    const float* lidar = (const float*)d_in[0];
    const float* cam   = (const float*)d_in[1];
    const float* Wq    = (const float*)d_in[2];
    const float* Wk    = (const float*)d_in[3];
    const float* Wv    = (const float*)d_in[4];
    const float* Wo    = (const float*)d_in[5];

    ushort* ws = (ushort*)d_ws;
    const size_t M1 = (size_t)1 << 20;        // 1M elems
    const size_t TT = (size_t)16 << 20;       // 16M elems = one [2][8192][1024] tensor
    ushort* Wqb  = ws;
    ushort* Wkb  = ws + M1;
    ushort* Wvb  = ws + 2 * M1;
    ushort* Wob  = ws + 3 * M1;
    ushort* lidT = ws + 4 * M1;
    ushort* camT = lidT + TT;
    ushort* qb   = camT + TT;
    ushort* kb   = qb + TT;
    ushort* vb   = kb + TT;
    ushort* aoT  = lidT;                      // reuse (lidar_T dead after q GEMM)

    const dim3 blk(256);
    conv_w4<<<dim3(512, 4), blk, 0, stream>>>(Wq, Wk, Wv, Wo, ws);
    transpose_cvt<true><<<dim3(128, 16, 2), blk, 0, stream>>>(lidar, lidT);
    transpose_cvt<true><<<dim3(128, 16, 2), blk, 0, stream>>>(cam, camT);

    gemm_bt<0><<<dim3(1024), blk, 0, stream>>>(Wqb, lidT, qb);
    gemm_bt<0><<<dim3(1024), blk, 0, stream>>>(Wkb, camT, kb);
    gemm_bt<0><<<dim3(1024), blk, 0, stream>>>(Wvb, camT, vb);

    attn_kernel<<<dim3(2048), blk, 0, stream>>>(qb, kb, vb, qb);

    transpose_cvt<false><<<dim3(128, 16, 2), blk, 0, stream>>>(qb, aoT);
    gemm_bt<1><<<dim3(1024), blk, 0, stream>>>(Wob, aoT, (float*)d_out);
}

// Round 3
// 309.666 us; speedup vs baseline: 6.0917x; 1.4942x over previous
//
#include <hip/hip_runtime.h>
#include <math.h>

#define CH  1024
#define PPB 8192            // positions per batch (D*N = 64*128)

typedef __attribute__((ext_vector_type(8))) short short8;
typedef __attribute__((ext_vector_type(4))) float f32x4;

__device__ __forceinline__ ushort f2bf(float x) {
    uint u = __float_as_uint(x);
    return (ushort)((u + 0x7FFFu + ((u >> 16) & 1u)) >> 16);   // RNE
}
__device__ __forceinline__ float bf2f(ushort u) {
    return __uint_as_float(((uint)u) << 16);
}
__device__ __forceinline__ void gload16(const void* g, const void* l) {
    __builtin_amdgcn_global_load_lds((const __attribute__((address_space(1))) void*)g,
                                     (__attribute__((address_space(3))) void*)l, 16, 0, 0);
}

// ---------------------------------------------------------------------------
// Weight fp32 -> bf16 (4 x 1M elements)
// ---------------------------------------------------------------------------
__global__ __launch_bounds__(256) void conv_w4(const float* __restrict__ w0,
                                               const float* __restrict__ w1,
                                               const float* __restrict__ w2,
                                               const float* __restrict__ w3,
                                               ushort* __restrict__ dst)
{
    const int y = blockIdx.y;
    const float* w = (y == 0) ? w0 : (y == 1) ? w1 : (y == 2) ? w2 : w3;
    ushort* o = dst + (size_t)y * (1u << 20);
    const int idx = (blockIdx.x * 256 + threadIdx.x) * 8;
    const float4 v0 = *(const float4*)(w + idx);
    const float4 v1 = *(const float4*)(w + idx + 4);
    ushort4 o0, o1;
    o0.x = f2bf(v0.x); o0.y = f2bf(v0.y); o0.z = f2bf(v0.z); o0.w = f2bf(v0.w);
    o1.x = f2bf(v1.x); o1.y = f2bf(v1.y); o1.z = f2bf(v1.z); o1.w = f2bf(v1.w);
    *(ushort4*)(o + idx)     = o0;
    *(ushort4*)(o + idx + 4) = o1;
}

// ---------------------------------------------------------------------------
// Transpose + convert: in[b][c][s] -> out[b][p][c] bf16
// REMAP=false: p = s (plain transpose).
// REMAP=true : s = i*64+d  ->  p = d*128+i   (attn-out [c][i][d] -> [p][c])
//   within a 64-tile (s0 % 64 == 0): i = s0>>6 = blockIdx.x const, d = sl.
// ---------------------------------------------------------------------------
template <bool IN_F32, bool REMAP>
__global__ __launch_bounds__(256) void transpose_cvt(const void* __restrict__ in_,
                                                     ushort* __restrict__ out)
{
    __shared__ float T[64][65];
    const int p0 = blockIdx.x * 64;
    const int c0 = blockIdx.y * 64;
    const int b  = blockIdx.z;
    const int t  = threadIdx.x;
    const int rc = t >> 4;            // 0..15
    const int rp = (t & 15) * 4;      // 0..60

    #pragma unroll
    for (int pass = 0; pass < 4; ++pass) {
        const int c = pass * 16 + rc;
        const size_t base = ((size_t)(b * CH + c0 + c)) * PPB + p0 + rp;
        if (IN_F32) {
            const float4 v = *(const float4*)((const float*)in_ + base);
            T[c][rp] = v.x; T[c][rp + 1] = v.y; T[c][rp + 2] = v.z; T[c][rp + 3] = v.w;
        } else {
            const ushort4 v = *(const ushort4*)((const ushort*)in_ + base);
            T[c][rp]     = bf2f(v.x); T[c][rp + 1] = bf2f(v.y);
            T[c][rp + 2] = bf2f(v.z); T[c][rp + 3] = bf2f(v.w);
        }
    }
    __syncthreads();
    #pragma unroll
    for (int pass = 0; pass < 4; ++pass) {
        const int p = pass * 16 + rc;                    // tile-local s
        const int prow = REMAP ? (p * 128 + blockIdx.x) : (p0 + p);
        ushort4 o;
        o.x = f2bf(T[rp + 0][p]); o.y = f2bf(T[rp + 1][p]);
        o.z = f2bf(T[rp + 2][p]); o.w = f2bf(T[rp + 3][p]);
        *(ushort4*)(out + ((size_t)(b * PPB + prow)) * CH + c0 + rp) = o;
    }
}

// ---------------------------------------------------------------------------
// bf16 MFMA GEMM (m97 structure): C[m][n] = sum_k A[m][k] * Bt[row(n)][k]
// BMAP 0: row(n) = bn*128 + n (linear positions).
// BMAP 1: row(n) = b*8192 + (n&63)*128 + (bn&63)*2 + (n>>6)
//         -> output column p0+n holds position (d=n&63, i=i0+(n>>6)),
//            i.e. C is written in [b][c][i][d] layout with NO epilogue change.
// MODE 0: write bf16. MODE 1: write f32 gelu.
// ---------------------------------------------------------------------------
template <int MODE, int BMAP>
__global__ __launch_bounds__(256) void gemm_bt(const ushort* __restrict__ A,
                                               const ushort* __restrict__ Bt,
                                               void* __restrict__ Cout)
{
    __shared__ ushort As[2][128 * 32];
    __shared__ ushort Bs[2][128 * 32];

    const int bid = blockIdx.x;
    const int sid = (bid & 7) * 128 + (bid >> 3);  // XCD swizzle (1024 % 8 == 0)
    const int bm  = sid & 7;
    const int bn  = sid >> 3;                   // 0..127
    const int m0  = bm * 128;
    const int n0g = bn * 128;
    const int b   = bn >> 6;
    const int p0  = (bn & 63) * 128;
    const int i0  = (bn & 63) * 2;

    const int tid = threadIdx.x;
    const int w   = tid >> 6;
    const int l   = tid & 63;
    const int wr  = w >> 1, wc = w & 1;

    f32x4 acc[4][4];
    #pragma unroll
    for (int i = 0; i < 4; ++i)
        #pragma unroll
        for (int j = 0; j < 4; ++j) acc[i][j] = (f32x4)(0.0f);

    auto stage = [&](int buf, int kt) {
        const int k0 = kt * 32;
        #pragma unroll
        for (int i = 0; i < 2; ++i) {
            const int c = w * 2 + i;            // chunk 0..7 (16 rows each)
            const int r = c * 16 + (l >> 2);
            const int ke = k0 + (l & 3) * 8;
            gload16(A + (size_t)(m0 + r) * CH + ke, &As[buf][c * 512]);
            size_t brow;
            if (BMAP == 0) brow = (size_t)(n0g + r);
            else           brow = (size_t)b * PPB + (size_t)(r & 63) * 128 + i0 + (r >> 6);
            gload16(Bt + brow * CH + ke, &Bs[buf][c * 512]);
        }
    };

    stage(0, 0);
    int buf = 0;
    const int ks = (l >> 4) * 8;
    const int fr = l & 15;
    for (int kt = 0; kt < 32; ++kt) {
        __syncthreads();
        if (kt + 1 < 32) stage(buf ^ 1, kt + 1);
        short8 af[4], bfr[4];
        #pragma unroll
        for (int fm = 0; fm < 4; ++fm)
            af[fm] = *reinterpret_cast<const short8*>(
                &As[buf][(wr * 64 + fm * 16 + fr) * 32 + ks]);
        #pragma unroll
        for (int fn = 0; fn < 4; ++fn)
            bfr[fn] = *reinterpret_cast<const short8*>(
                &Bs[buf][(wc * 64 + fn * 16 + fr) * 32 + ks]);
        #pragma unroll
        for (int fm = 0; fm < 4; ++fm)
            #pragma unroll
            for (int fn = 0; fn < 4; ++fn)
                acc[fm][fn] = __builtin_amdgcn_mfma_f32_16x16x32_bf16(
                    af[fm], bfr[fn], acc[fm][fn], 0, 0, 0);
        buf ^= 1;
    }

    const int rq = l >> 4;
    #pragma unroll
    for (int fm = 0; fm < 4; ++fm) {
        #pragma unroll
        for (int fn = 0; fn < 4; ++fn) {
            #pragma unroll
            for (int r = 0; r < 4; ++r) {
                const int m = m0 + wr * 64 + fm * 16 + rq * 4 + r;
                const int n = wc * 64 + fn * 16 + fr;
                const float vv = acc[fm][fn][r];
                const size_t off = (size_t)b * CH * PPB + (size_t)m * PPB + p0 + n;
                if (MODE == 0) {
                    ((ushort*)Cout)[off] = f2bf(vv);
                } else {
                    ((float*)Cout)[off] = 0.5f * vv * (1.0f + erff(vv * 0.70710678118654752f));
                }
            }
        }
    }
}

// ---------------------------------------------------------------------------
// MFMA attention, one (b,h) per block, 4 waves; wave w owns query rows
// [w*32, w*32+32). Inputs: qt,kt = [b][c][i][d] bf16 (d-contig);
// vn = [b][c][d][j] bf16 (j-contig). Output ot = [b][c][i][d] bf16.
// All LDS tiles XOR-swizzled (T21: pre-swizzled global source + swizzled
// ds_read) so every fragment read is bank-conflict-free.
// ---------------------------------------------------------------------------
__global__ __launch_bounds__(256, 2) void attn_mfma(const ushort* __restrict__ qt,
                                                    const ushort* __restrict__ kt,
                                                    const ushort* __restrict__ vn,
                                                    ushort* __restrict__ ot)
{
    __shared__ ushort Qs[8192];    // [i=128][d=64], block-swizzled ^ (i&7)
    __shared__ ushort Ks[8192];    // [j=128][d=64], ^ (j&7)
    __shared__ ushort Vs[8192];    // [d=64][j=128], ^ (d&15)
    __shared__ ushort Ps[16384];   // [i=128][j=128], ^ (i&15)

    const int bh  = blockIdx.x;
    const int tid = threadIdx.x;
    const int w   = tid >> 6;
    const int l   = tid & 63;
    const int hi  = l >> 4;
    const int fr  = l & 15;
    const size_t base = (size_t)bh * 8192;

    // ---- stage Q, K, V (global_load_lds, swizzled global source) ----
    {
        const int lr = l >> 3, lb = l & 7;       // Q/K: 8 rows x 8 blocks per 1KB chunk
        const int vr = l >> 4, vbk = l & 15;     // V:   4 rows x 16 blocks per 1KB chunk
        #pragma unroll
        for (int q = 0; q < 4; ++q) {
            const int ch = w * 4 + q;
            const int i  = ch * 8 + lr;
            gload16(qt + base + i * 64 + ((lb ^ (i & 7)) << 3), &Qs[ch * 512]);
            gload16(kt + base + i * 64 + ((lb ^ (i & 7)) << 3), &Ks[ch * 512]);
            const int d  = ch * 4 + vr;
            gload16(vn + base + d * 128 + ((vbk ^ (d & 15)) << 3), &Vs[ch * 512]);
        }
    }
    __syncthreads();

    // ---- S = Q^T K  (strip rows i0w..i0w+31, all 128 j) ----
    const int i0w = w * 32;
    f32x4 accS[2][8];
    #pragma unroll
    for (int a = 0; a < 2; ++a)
        #pragma unroll
        for (int bjj = 0; bjj < 8; ++bjj) accS[a][bjj] = (f32x4)(0.0f);

    #pragma unroll
    for (int kk = 0; kk < 2; ++kk) {
        const int blk = kk * 4 + hi;
        short8 aq[2];
        #pragma unroll
        for (int fm = 0; fm < 2; ++fm) {
            const int i = i0w + fm * 16 + fr;
            aq[fm] = *(const short8*)&Qs[i * 64 + ((blk ^ (i & 7)) << 3)];
        }
        #pragma unroll
        for (int fn = 0; fn < 8; ++fn) {
            const int j = fn * 16 + fr;
            const short8 bk = *(const short8*)&Ks[j * 64 + ((blk ^ (j & 7)) << 3)];
            #pragma unroll
            for (int fm = 0; fm < 2; ++fm)
                accS[fm][fn] = __builtin_amdgcn_mfma_f32_16x16x32_bf16(
                    aq[fm], bk, accS[fm][fn], 0, 0, 0);
        }
    }

    // ---- row softmax (rows live in 16 consecutive lanes sharing hi) ----
    const float CS = 0.125f * 1.44269504088896341f;   // scale * log2(e)
    #pragma unroll
    for (int fm = 0; fm < 2; ++fm) {
        #pragma unroll
        for (int r = 0; r < 4; ++r) {
            float mx = accS[fm][0][r];
            #pragma unroll
            for (int fn = 1; fn < 8; ++fn) mx = fmaxf(mx, accS[fm][fn][r]);
            #pragma unroll
            for (int msk = 1; msk <= 8; msk <<= 1) mx = fmaxf(mx, __shfl_xor(mx, msk, 64));
            float e[8], sum = 0.f;
            #pragma unroll
            for (int fn = 0; fn < 8; ++fn) {
                e[fn] = exp2f((accS[fm][fn][r] - mx) * CS);
                sum += e[fn];
            }
            #pragma unroll
            for (int msk = 1; msk <= 8; msk <<= 1) sum += __shfl_xor(sum, msk, 64);
            const float is = 1.0f / sum;
            const int i = i0w + fm * 16 + hi * 4 + r;
            #pragma unroll
            for (int fn = 0; fn < 8; ++fn) {
                const int j = fn * 16 + fr;
                Ps[i * 128 + (((j >> 3) ^ (i & 15)) << 3) + (j & 7)] = f2bf(e[fn] * is);
            }
        }
    }
    // no barrier: each wave reads only its own P rows (A-operand below)

    // ---- O = P V^T : C[i][d] = sum_j P[i][j] V[d][j] ----
    f32x4 accO[2][4];
    #pragma unroll
    for (int a = 0; a < 2; ++a)
        #pragma unroll
        for (int bjj = 0; bjj < 4; ++bjj) accO[a][bjj] = (f32x4)(0.0f);

    #pragma unroll
    for (int ks2 = 0; ks2 < 4; ++ks2) {
        const int blk = ks2 * 4 + hi;
        short8 ap[2];
        #pragma unroll
        for (int fm = 0; fm < 2; ++fm) {
            const int i = i0w + fm * 16 + fr;
            ap[fm] = *(const short8*)&Ps[i * 128 + ((blk ^ (i & 15)) << 3)];
        }
        #pragma unroll
        for (int fn2 = 0; fn2 < 4; ++fn2) {
            const int d = fn2 * 16 + fr;
            const short8 bv = *(const short8*)&Vs[d * 128 + ((blk ^ (d & 15)) << 3)];
            #pragma unroll
            for (int fm = 0; fm < 2; ++fm)
                accO[fm][fn2] = __builtin_amdgcn_mfma_f32_16x16x32_bf16(
                    ap[fm], bv, accO[fm][fn2], 0, 0, 0);
        }
    }

    // ---- write O_t[i][d] bf16 (coalesced 32B runs, merges in L2) ----
    #pragma unroll
    for (int fm = 0; fm < 2; ++fm)
        #pragma unroll
        for (int fn2 = 0; fn2 < 4; ++fn2)
            #pragma unroll
            for (int r = 0; r < 4; ++r) {
                const int i = i0w + fm * 16 + hi * 4 + r;
                const int d = fn2 * 16 + fr;
                ot[base + i * 64 + d] = f2bf(accO[fm][fn2][r]);
            }
}

// ---------------------------------------------------------------------------
extern "C" void kernel_launch(void* const* d_in, const int* in_sizes, int n_in,
                              void* d_out, int out_size, void* d_ws, size_t ws_size,
                              hipStream_t stream)
{
    const float* lidar = (const float*)d_in[0];
    const float* cam   = (const float*)d_in[1];
    const float* Wq    = (const float*)d_in[2];
    const float* Wk    = (const float*)d_in[3];
    const float* Wv    = (const float*)d_in[4];
    const float* Wo    = (const float*)d_in[5];

    ushort* ws = (ushort*)d_ws;
    const size_t M1 = (size_t)1 << 20;
    const size_t TT = (size_t)16 << 20;
    ushort* Wqb  = ws;
    ushort* Wkb  = ws + M1;
    ushort* Wvb  = ws + 2 * M1;
    ushort* Wob  = ws + 3 * M1;
    ushort* lidT = ws + 4 * M1;
    ushort* camT = lidT + TT;
    ushort* qb   = camT + TT;   // q_t [b][c][i][d]; attn overwrites with O_t
    ushort* kb   = qb + TT;     // k_t [b][c][j][d]
    ushort* vb   = kb + TT;     // v   [b][c][d][j]
    ushort* aoT  = lidT;        // reuse (lidT dead after q GEMM)

    const dim3 blk(256);
    conv_w4<<<dim3(512, 4), blk, 0, stream>>>(Wq, Wk, Wv, Wo, ws);
    transpose_cvt<true, false><<<dim3(128, 16, 2), blk, 0, stream>>>(lidar, lidT);
    transpose_cvt<true, false><<<dim3(128, 16, 2), blk, 0, stream>>>(cam, camT);

    gemm_bt<0, 1><<<dim3(1024), blk, 0, stream>>>(Wqb, lidT, qb);
    gemm_bt<0, 1><<<dim3(1024), blk, 0, stream>>>(Wkb, camT, kb);
    gemm_bt<0, 0><<<dim3(1024), blk, 0, stream>>>(Wvb, camT, vb);

    attn_mfma<<<dim3(2048), blk, 0, stream>>>(qb, kb, vb, qb);

    transpose_cvt<false, true><<<dim3(128, 16, 2), blk, 0, stream>>>(qb, aoT);
    gemm_bt<1, 0><<<dim3(1024), blk, 0, stream>>>(Wob, aoT, (float*)d_out);
}

// Round 4
// 289.768 us; speedup vs baseline: 6.5100x; 1.0687x over previous
//
#include <hip/hip_runtime.h>
#include <math.h>

#define CH  1024
#define PPB 8192            // positions per batch (D*N = 64*128)

typedef __attribute__((ext_vector_type(8))) short short8;
typedef __attribute__((ext_vector_type(4))) float f32x4;

__device__ __forceinline__ ushort f2bf(float x) {
    uint u = __float_as_uint(x);
    return (ushort)((u + 0x7FFFu + ((u >> 16) & 1u)) >> 16);   // RNE
}
__device__ __forceinline__ float bf2f(ushort u) {
    return __uint_as_float(((uint)u) << 16);
}
__device__ __forceinline__ void gload16(const void* g, const void* l) {
    __builtin_amdgcn_global_load_lds((const __attribute__((address_space(1))) void*)g,
                                     (__attribute__((address_space(3))) void*)l, 16, 0, 0);
}

// ---------------------------------------------------------------------------
// Fused prep: [0,2048) weight fp32->bf16; [2048,6144) lidar transpose;
// [6144,10240) cam transpose.  transpose: in[b][c][p] f32 -> out[b][p][c] bf16
// ---------------------------------------------------------------------------
__global__ __launch_bounds__(256) void prep(const float* __restrict__ lidar,
                                            const float* __restrict__ cam,
                                            const float* __restrict__ Wq,
                                            const float* __restrict__ Wk,
                                            const float* __restrict__ Wv,
                                            const float* __restrict__ Wo,
                                            ushort* __restrict__ wdst,
                                            ushort* __restrict__ lidT,
                                            ushort* __restrict__ camT)
{
    __shared__ float T[64][65];
    const int blk = blockIdx.x;
    const int tid = threadIdx.x;

    if (blk < 2048) {      // ---- weight convert: 4 x 1M elems ----
        const int y = blk >> 9;
        const int x = blk & 511;
        const float* w = (y == 0) ? Wq : (y == 1) ? Wk : (y == 2) ? Wv : Wo;
        ushort* o = wdst + (size_t)y * (1u << 20);
        const int idx = (x * 256 + tid) * 8;
        const float4 v0 = *(const float4*)(w + idx);
        const float4 v1 = *(const float4*)(w + idx + 4);
        ushort4 o0, o1;
        o0.x = f2bf(v0.x); o0.y = f2bf(v0.y); o0.z = f2bf(v0.z); o0.w = f2bf(v0.w);
        o1.x = f2bf(v1.x); o1.y = f2bf(v1.y); o1.z = f2bf(v1.z); o1.w = f2bf(v1.w);
        *(ushort4*)(o + idx)     = o0;
        *(ushort4*)(o + idx + 4) = o1;
        return;
    }

    // ---- transpose+convert ----
    const int t = blk - 2048;
    const bool isLid = (t < 4096);
    const int tt = isLid ? t : t - 4096;
    const float* in = isLid ? lidar : cam;
    ushort* out = isLid ? lidT : camT;

    const int p0 = (tt & 127) * 64;
    const int c0 = ((tt >> 7) & 15) * 64;
    const int b  = tt >> 11;
    const int rc = tid >> 4;            // 0..15
    const int rp = (tid & 15) * 4;      // 0..60

    #pragma unroll
    for (int pass = 0; pass < 4; ++pass) {
        const int c = pass * 16 + rc;
        const size_t base = ((size_t)(b * CH + c0 + c)) * PPB + p0 + rp;
        const float4 v = *(const float4*)(in + base);
        T[c][rp] = v.x; T[c][rp + 1] = v.y; T[c][rp + 2] = v.z; T[c][rp + 3] = v.w;
    }
    __syncthreads();
    #pragma unroll
    for (int pass = 0; pass < 4; ++pass) {
        const int p = pass * 16 + rc;
        ushort4 o;
        o.x = f2bf(T[rp + 0][p]); o.y = f2bf(T[rp + 1][p]);
        o.z = f2bf(T[rp + 2][p]); o.w = f2bf(T[rp + 3][p]);
        *(ushort4*)(out + ((size_t)(b * PPB + p0 + p)) * CH + c0 + rp) = o;
    }
}

// ---------------------------------------------------------------------------
// bf16 transpose with attn-out remap: in[b][c][s] bf16 (s=i*64+d) ->
// out[b][d*128+i][c] bf16
// ---------------------------------------------------------------------------
__global__ __launch_bounds__(256) void transpose_ao(const ushort* __restrict__ in_,
                                                    ushort* __restrict__ out)
{
    __shared__ float T[64][65];
    const int p0 = blockIdx.x * 64;
    const int c0 = blockIdx.y * 64;
    const int b  = blockIdx.z;
    const int t  = threadIdx.x;
    const int rc = t >> 4;
    const int rp = (t & 15) * 4;

    #pragma unroll
    for (int pass = 0; pass < 4; ++pass) {
        const int c = pass * 16 + rc;
        const size_t base = ((size_t)(b * CH + c0 + c)) * PPB + p0 + rp;
        const ushort4 v = *(const ushort4*)(in_ + base);
        T[c][rp]     = bf2f(v.x); T[c][rp + 1] = bf2f(v.y);
        T[c][rp + 2] = bf2f(v.z); T[c][rp + 3] = bf2f(v.w);
    }
    __syncthreads();
    #pragma unroll
    for (int pass = 0; pass < 4; ++pass) {
        const int p = pass * 16 + rc;                    // tile-local s
        const int prow = p * 128 + blockIdx.x;           // s=i*64+d -> p=d*128+i
        ushort4 o;
        o.x = f2bf(T[rp + 0][p]); o.y = f2bf(T[rp + 1][p]);
        o.z = f2bf(T[rp + 2][p]); o.w = f2bf(T[rp + 3][p]);
        *(ushort4*)(out + ((size_t)(b * PPB + prow)) * CH + c0 + rp) = o;
    }
}

// ---------------------------------------------------------------------------
// Merged q/k/v GEMM: 3072 blocks; g = block's third (0:q, 1:k, 2:v).
// C[m][n] = sum_k W3[g][m][k] * Bt[row(n)][k].
// g<2 (q,k): row remap -> output in [b][c][i][d] layout (position-transposed).
// g==2 (v): linear rows -> output [b][c][d][j].
// ---------------------------------------------------------------------------
__global__ __launch_bounds__(256) void gemm_qkv(const ushort* __restrict__ W3,
                                                const ushort* __restrict__ lidT,
                                                const ushort* __restrict__ camT,
                                                ushort* __restrict__ out3)
{
    __shared__ ushort As[2][128 * 32];
    __shared__ ushort Bs[2][128 * 32];

    const int bid = blockIdx.x;                    // 0..3071
    const int sid = (bid & 7) * 384 + (bid >> 3);  // XCD swizzle (3072%8==0)
    const int g   = sid >> 10;                     // 0:q 1:k 2:v
    const int r0  = sid & 1023;
    const int bm  = r0 & 7;
    const int bn  = r0 >> 3;                       // 0..127
    const int m0  = bm * 128;
    const int n0g = bn * 128;
    const int b   = bn >> 6;
    const int p0  = (bn & 63) * 128;
    const int i0  = (bn & 63) * 2;

    const ushort* A  = W3 + (size_t)g * (1u << 20);
    const ushort* Bt = (g == 0) ? lidT : camT;
    const bool remap = (g < 2);
    ushort* Cout = out3 + (size_t)g * ((size_t)16 << 20);

    const int tid = threadIdx.x;
    const int w   = tid >> 6;
    const int l   = tid & 63;
    const int wr  = w >> 1, wc = w & 1;

    f32x4 acc[4][4];
    #pragma unroll
    for (int i = 0; i < 4; ++i)
        #pragma unroll
        for (int j = 0; j < 4; ++j) acc[i][j] = (f32x4)(0.0f);

    auto stage = [&](int buf, int kt) {
        const int k0 = kt * 32;
        #pragma unroll
        for (int i = 0; i < 2; ++i) {
            const int c  = w * 2 + i;               // chunk 0..7 (16 rows each)
            const int rr = c * 16 + (l >> 2);
            const int ke = k0 + (l & 3) * 8;
            gload16(A + (size_t)(m0 + rr) * CH + ke, &As[buf][c * 512]);
            size_t brow;
            if (remap) brow = (size_t)b * PPB + (size_t)(rr & 63) * 128 + i0 + (rr >> 6);
            else       brow = (size_t)(n0g + rr);
            gload16(Bt + brow * CH + ke, &Bs[buf][c * 512]);
        }
    };

    stage(0, 0);
    int buf = 0;
    const int ks = (l >> 4) * 8;
    const int fr = l & 15;
    for (int kt = 0; kt < 32; ++kt) {
        __syncthreads();
        if (kt + 1 < 32) stage(buf ^ 1, kt + 1);
        short8 af[4], bfr[4];
        #pragma unroll
        for (int fm = 0; fm < 4; ++fm)
            af[fm] = *reinterpret_cast<const short8*>(
                &As[buf][(wr * 64 + fm * 16 + fr) * 32 + ks]);
        #pragma unroll
        for (int fn = 0; fn < 4; ++fn)
            bfr[fn] = *reinterpret_cast<const short8*>(
                &Bs[buf][(wc * 64 + fn * 16 + fr) * 32 + ks]);
        #pragma unroll
        for (int fm = 0; fm < 4; ++fm)
            #pragma unroll
            for (int fn = 0; fn < 4; ++fn)
                acc[fm][fn] = __builtin_amdgcn_mfma_f32_16x16x32_bf16(
                    af[fm], bfr[fn], acc[fm][fn], 0, 0, 0);
        buf ^= 1;
    }

    const int rq = l >> 4;
    #pragma unroll
    for (int fm = 0; fm < 4; ++fm)
        #pragma unroll
        for (int fn = 0; fn < 4; ++fn)
            #pragma unroll
            for (int r = 0; r < 4; ++r) {
                const int m = m0 + wr * 64 + fm * 16 + rq * 4 + r;
                const int n = wc * 64 + fn * 16 + fr;
                const size_t off = (size_t)b * CH * PPB + (size_t)m * PPB + p0 + n;
                ((ushort*)Cout)[off] = f2bf(acc[fm][fn][r]);
            }
}

// ---------------------------------------------------------------------------
// Wo GEMM (m97 structure): C[m][n] = gelu( sum_k A[m][k] * Bt[n][k] ), f32 out
// ---------------------------------------------------------------------------
__global__ __launch_bounds__(256) void gemm_wo(const ushort* __restrict__ A,
                                               const ushort* __restrict__ Bt,
                                               float* __restrict__ Cout)
{
    __shared__ ushort As[2][128 * 32];
    __shared__ ushort Bs[2][128 * 32];

    const int bid = blockIdx.x;
    const int sid = (bid & 7) * 128 + (bid >> 3);
    const int bm  = sid & 7;
    const int bn  = sid >> 3;
    const int m0  = bm * 128;
    const int n0g = bn * 128;
    const int b   = bn >> 6;
    const int p0  = (bn & 63) * 128;

    const int tid = threadIdx.x;
    const int w   = tid >> 6;
    const int l   = tid & 63;
    const int wr  = w >> 1, wc = w & 1;

    f32x4 acc[4][4];
    #pragma unroll
    for (int i = 0; i < 4; ++i)
        #pragma unroll
        for (int j = 0; j < 4; ++j) acc[i][j] = (f32x4)(0.0f);

    auto stage = [&](int buf, int kt) {
        const int k0 = kt * 32;
        #pragma unroll
        for (int i = 0; i < 2; ++i) {
            const int c  = w * 2 + i;
            const int rr = c * 16 + (l >> 2);
            const int ke = k0 + (l & 3) * 8;
            gload16(A  + (size_t)(m0 + rr) * CH + ke, &As[buf][c * 512]);
            gload16(Bt + (size_t)(n0g + rr) * CH + ke, &Bs[buf][c * 512]);
        }
    };

    stage(0, 0);
    int buf = 0;
    const int ks = (l >> 4) * 8;
    const int fr = l & 15;
    for (int kt = 0; kt < 32; ++kt) {
        __syncthreads();
        if (kt + 1 < 32) stage(buf ^ 1, kt + 1);
        short8 af[4], bfr[4];
        #pragma unroll
        for (int fm = 0; fm < 4; ++fm)
            af[fm] = *reinterpret_cast<const short8*>(
                &As[buf][(wr * 64 + fm * 16 + fr) * 32 + ks]);
        #pragma unroll
        for (int fn = 0; fn < 4; ++fn)
            bfr[fn] = *reinterpret_cast<const short8*>(
                &Bs[buf][(wc * 64 + fn * 16 + fr) * 32 + ks]);
        #pragma unroll
        for (int fm = 0; fm < 4; ++fm)
            #pragma unroll
            for (int fn = 0; fn < 4; ++fn)
                acc[fm][fn] = __builtin_amdgcn_mfma_f32_16x16x32_bf16(
                    af[fm], bfr[fn], acc[fm][fn], 0, 0, 0);
        buf ^= 1;
    }

    const int rq = l >> 4;
    #pragma unroll
    for (int fm = 0; fm < 4; ++fm)
        #pragma unroll
        for (int fn = 0; fn < 4; ++fn)
            #pragma unroll
            for (int r = 0; r < 4; ++r) {
                const int m = m0 + wr * 64 + fm * 16 + rq * 4 + r;
                const int n = wc * 64 + fn * 16 + fr;
                const float vv = acc[fm][fn][r];
                const size_t off = (size_t)b * CH * PPB + (size_t)m * PPB + p0 + n;
                Cout[off] = 0.5f * vv * (1.0f + erff(vv * 0.70710678118654752f));
            }
}

// ---------------------------------------------------------------------------
// MFMA attention, one (b,h) per block, 4 waves (unchanged from round 3).
// ---------------------------------------------------------------------------
__global__ __launch_bounds__(256, 2) void attn_mfma(const ushort* __restrict__ qt,
                                                    const ushort* __restrict__ kt,
                                                    const ushort* __restrict__ vn,
                                                    ushort* __restrict__ ot)
{
    __shared__ ushort Qs[8192];
    __shared__ ushort Ks[8192];
    __shared__ ushort Vs[8192];
    __shared__ ushort Ps[16384];

    const int bh  = blockIdx.x;
    const int tid = threadIdx.x;
    const int w   = tid >> 6;
    const int l   = tid & 63;
    const int hi  = l >> 4;
    const int fr  = l & 15;
    const size_t base = (size_t)bh * 8192;

    {
        const int lr = l >> 3, lb = l & 7;
        const int vr = l >> 4, vbk = l & 15;
        #pragma unroll
        for (int q = 0; q < 4; ++q) {
            const int ch = w * 4 + q;
            const int i  = ch * 8 + lr;
            gload16(qt + base + i * 64 + ((lb ^ (i & 7)) << 3), &Qs[ch * 512]);
            gload16(kt + base + i * 64 + ((lb ^ (i & 7)) << 3), &Ks[ch * 512]);
            const int d  = ch * 4 + vr;
            gload16(vn + base + d * 128 + ((vbk ^ (d & 15)) << 3), &Vs[ch * 512]);
        }
    }
    __syncthreads();

    const int i0w = w * 32;
    f32x4 accS[2][8];
    #pragma unroll
    for (int a = 0; a < 2; ++a)
        #pragma unroll
        for (int bjj = 0; bjj < 8; ++bjj) accS[a][bjj] = (f32x4)(0.0f);

    #pragma unroll
    for (int kk = 0; kk < 2; ++kk) {
        const int blk = kk * 4 + hi;
        short8 aq[2];
        #pragma unroll
        for (int fm = 0; fm < 2; ++fm) {
            const int i = i0w + fm * 16 + fr;
            aq[fm] = *(const short8*)&Qs[i * 64 + ((blk ^ (i & 7)) << 3)];
        }
        #pragma unroll
        for (int fn = 0; fn < 8; ++fn) {
            const int j = fn * 16 + fr;
            const short8 bk = *(const short8*)&Ks[j * 64 + ((blk ^ (j & 7)) << 3)];
            #pragma unroll
            for (int fm = 0; fm < 2; ++fm)
                accS[fm][fn] = __builtin_amdgcn_mfma_f32_16x16x32_bf16(
                    aq[fm], bk, accS[fm][fn], 0, 0, 0);
        }
    }

    const float CS = 0.125f * 1.44269504088896341f;
    #pragma unroll
    for (int fm = 0; fm < 2; ++fm) {
        #pragma unroll
        for (int r = 0; r < 4; ++r) {
            float mx = accS[fm][0][r];
            #pragma unroll
            for (int fn = 1; fn < 8; ++fn) mx = fmaxf(mx, accS[fm][fn][r]);
            #pragma unroll
            for (int msk = 1; msk <= 8; msk <<= 1) mx = fmaxf(mx, __shfl_xor(mx, msk, 64));
            float e[8], sum = 0.f;
            #pragma unroll
            for (int fn = 0; fn < 8; ++fn) {
                e[fn] = exp2f((accS[fm][fn][r] - mx) * CS);
                sum += e[fn];
            }
            #pragma unroll
            for (int msk = 1; msk <= 8; msk <<= 1) sum += __shfl_xor(sum, msk, 64);
            const float is = 1.0f / sum;
            const int i = i0w + fm * 16 + hi * 4 + r;
            #pragma unroll
            for (int fn = 0; fn < 8; ++fn) {
                const int j = fn * 16 + fr;
                Ps[i * 128 + (((j >> 3) ^ (i & 15)) << 3) + (j & 7)] = f2bf(e[fn] * is);
            }
        }
    }

    f32x4 accO[2][4];
    #pragma unroll
    for (int a = 0; a < 2; ++a)
        #pragma unroll
        for (int bjj = 0; bjj < 4; ++bjj) accO[a][bjj] = (f32x4)(0.0f);

    #pragma unroll
    for (int ks2 = 0; ks2 < 4; ++ks2) {
        const int blk = ks2 * 4 + hi;
        short8 ap[2];
        #pragma unroll
        for (int fm = 0; fm < 2; ++fm) {
            const int i = i0w + fm * 16 + fr;
            ap[fm] = *(const short8*)&Ps[i * 128 + ((blk ^ (i & 15)) << 3)];
        }
        #pragma unroll
        for (int fn2 = 0; fn2 < 4; ++fn2) {
            const int d = fn2 * 16 + fr;
            const short8 bv = *(const short8*)&Vs[d * 128 + ((blk ^ (d & 15)) << 3)];
            #pragma unroll
            for (int fm = 0; fm < 2; ++fm)
                accO[fm][fn2] = __builtin_amdgcn_mfma_f32_16x16x32_bf16(
                    ap[fm], bv, accO[fm][fn2], 0, 0, 0);
        }
    }

    #pragma unroll
    for (int fm = 0; fm < 2; ++fm)
        #pragma unroll
        for (int fn2 = 0; fn2 < 4; ++fn2)
            #pragma unroll
            for (int r = 0; r < 4; ++r) {
                const int i = i0w + fm * 16 + hi * 4 + r;
                const int d = fn2 * 16 + fr;
                ot[base + i * 64 + d] = f2bf(accO[fm][fn2][r]);
            }
}

// ---------------------------------------------------------------------------
extern "C" void kernel_launch(void* const* d_in, const int* in_sizes, int n_in,
                              void* d_out, int out_size, void* d_ws, size_t ws_size,
                              hipStream_t stream)
{
    const float* lidar = (const float*)d_in[0];
    const float* cam   = (const float*)d_in[1];
    const float* Wq    = (const float*)d_in[2];
    const float* Wk    = (const float*)d_in[3];
    const float* Wv    = (const float*)d_in[4];
    const float* Wo    = (const float*)d_in[5];

    ushort* ws = (ushort*)d_ws;
    const size_t M1 = (size_t)1 << 20;
    const size_t TT = (size_t)16 << 20;
    ushort* Wob  = ws + 3 * M1;
    ushort* lidT = ws + 4 * M1;
    ushort* camT = lidT + TT;
    ushort* qb   = camT + TT;   // q_t [b][c][i][d]; attn overwrites with O_t
    ushort* aoT  = lidT;        // reuse (lidT dead after q GEMM)

    const dim3 blk(256);
    prep<<<dim3(10240), blk, 0, stream>>>(lidar, cam, Wq, Wk, Wv, Wo, ws, lidT, camT);

    gemm_qkv<<<dim3(3072), blk, 0, stream>>>(ws, lidT, camT, qb);

    attn_mfma<<<dim3(2048), blk, 0, stream>>>(qb, qb + TT, qb + 2 * TT, qb);

    transpose_ao<<<dim3(128, 16, 2), blk, 0, stream>>>(qb, aoT);

    gemm_wo<<<dim3(1024), blk, 0, stream>>>(Wob, aoT, (float*)d_out);
}

// Round 6
// 268.332 us; speedup vs baseline: 7.0300x; 1.0799x over previous
//
#include <hip/hip_runtime.h>
#include <math.h>

#define CH  1024
#define PPB 8192            // positions per batch (D*N = 64*128)

typedef __attribute__((ext_vector_type(8))) short short8;
typedef __attribute__((ext_vector_type(4))) float f32x4;

__device__ __forceinline__ ushort f2bf(float x) {
    uint u = __float_as_uint(x);
    return (ushort)((u + 0x7FFFu + ((u >> 16) & 1u)) >> 16);   // RNE
}
__device__ __forceinline__ float bf2f(ushort u) {
    return __uint_as_float(((uint)u) << 16);
}
__device__ __forceinline__ void gload16(const void* g, const void* l) {
    __builtin_amdgcn_global_load_lds((const __attribute__((address_space(1))) void*)g,
                                     (__attribute__((address_space(3))) void*)l, 16, 0, 0);
}

// ---------------------------------------------------------------------------
// Fused prep: [0,2048) weight fp32->bf16; [2048,6144) lidar transpose;
// [6144,10240) cam transpose.  transpose: in[b][c][p] f32 -> out[b][p][c] bf16
// ---------------------------------------------------------------------------
__global__ __launch_bounds__(256) void prep(const float* __restrict__ lidar,
                                            const float* __restrict__ cam,
                                            const float* __restrict__ Wq,
                                            const float* __restrict__ Wk,
                                            const float* __restrict__ Wv,
                                            const float* __restrict__ Wo,
                                            ushort* __restrict__ wdst,
                                            ushort* __restrict__ lidT,
                                            ushort* __restrict__ camT)
{
    __shared__ float T[64][65];
    const int blk = blockIdx.x;
    const int tid = threadIdx.x;

    if (blk < 2048) {      // ---- weight convert: 4 x 1M elems ----
        const int y = blk >> 9;
        const int x = blk & 511;
        const float* w = (y == 0) ? Wq : (y == 1) ? Wk : (y == 2) ? Wv : Wo;
        ushort* o = wdst + (size_t)y * (1u << 20);
        const int idx = (x * 256 + tid) * 8;
        const float4 v0 = *(const float4*)(w + idx);
        const float4 v1 = *(const float4*)(w + idx + 4);
        ushort4 o0, o1;
        o0.x = f2bf(v0.x); o0.y = f2bf(v0.y); o0.z = f2bf(v0.z); o0.w = f2bf(v0.w);
        o1.x = f2bf(v1.x); o1.y = f2bf(v1.y); o1.z = f2bf(v1.z); o1.w = f2bf(v1.w);
        *(ushort4*)(o + idx)     = o0;
        *(ushort4*)(o + idx + 4) = o1;
        return;
    }

    // ---- transpose+convert ----
    const int t = blk - 2048;
    const bool isLid = (t < 4096);
    const int tt = isLid ? t : t - 4096;
    const float* in = isLid ? lidar : cam;
    ushort* out = isLid ? lidT : camT;

    const int p0 = (tt & 127) * 64;
    const int c0 = ((tt >> 7) & 15) * 64;
    const int b  = tt >> 11;
    const int rc = tid >> 4;            // 0..15
    const int rp = (tid & 15) * 4;      // 0..60

    #pragma unroll
    for (int pass = 0; pass < 4; ++pass) {
        const int c = pass * 16 + rc;
        const size_t base = ((size_t)(b * CH + c0 + c)) * PPB + p0 + rp;
        const float4 v = *(const float4*)(in + base);
        T[c][rp] = v.x; T[c][rp + 1] = v.y; T[c][rp + 2] = v.z; T[c][rp + 3] = v.w;
    }
    __syncthreads();
    #pragma unroll
    for (int pass = 0; pass < 4; ++pass) {
        const int p = pass * 16 + rc;
        ushort4 o;
        o.x = f2bf(T[rp + 0][p]); o.y = f2bf(T[rp + 1][p]);
        o.z = f2bf(T[rp + 2][p]); o.w = f2bf(T[rp + 3][p]);
        *(ushort4*)(out + ((size_t)(b * PPB + p0 + p)) * CH + c0 + rp) = o;
    }
}

// ---------------------------------------------------------------------------
// bf16 transpose with attn-out remap: in[b][c][s] bf16 (s=i*64+d) ->
// out[b][d*128+i][c] bf16
// ---------------------------------------------------------------------------
__global__ __launch_bounds__(256) void transpose_ao(const ushort* __restrict__ in_,
                                                    ushort* __restrict__ out)
{
    __shared__ float T[64][65];
    const int p0 = blockIdx.x * 64;
    const int c0 = blockIdx.y * 64;
    const int b  = blockIdx.z;
    const int t  = threadIdx.x;
    const int rc = t >> 4;
    const int rp = (t & 15) * 4;

    #pragma unroll
    for (int pass = 0; pass < 4; ++pass) {
        const int c = pass * 16 + rc;
        const size_t base = ((size_t)(b * CH + c0 + c)) * PPB + p0 + rp;
        const ushort4 v = *(const ushort4*)(in_ + base);
        T[c][rp]     = bf2f(v.x); T[c][rp + 1] = bf2f(v.y);
        T[c][rp + 2] = bf2f(v.z); T[c][rp + 3] = bf2f(v.w);
    }
    __syncthreads();
    #pragma unroll
    for (int pass = 0; pass < 4; ++pass) {
        const int p = pass * 16 + rc;                    // tile-local s
        const int prow = p * 128 + blockIdx.x;           // s=i*64+d -> p=d*128+i
        ushort4 o;
        o.x = f2bf(T[rp + 0][p]); o.y = f2bf(T[rp + 1][p]);
        o.z = f2bf(T[rp + 2][p]); o.w = f2bf(T[rp + 3][p]);
        *(ushort4*)(out + ((size_t)(b * PPB + prow)) * CH + c0 + rp) = o;
    }
}

// ---------------------------------------------------------------------------
// 256x256 8-phase bf16 MFMA GEMM (T2+T3+T4+T5), BK=64, 8 waves (2M x 4N),
// per-wave output 128x64. LDS 128KB = A[2][256][64] + B[2][256][64] bf16,
// XOR-swizzled (chunk ^= row&7, both-sides). Counted vmcnt (never 0 in loop).
// All waits pinned with sched_barrier(0) + "memory" (rule #18).
// IS_WO=0: 768 blocks, g=0:q(lidT,remap) 1:k(camT,remap) 2:v(camT,linear),
//          bf16 out3 + g*16M.  IS_WO=1: 256 blocks, g=3, B linear, f32 gelu.
// W3 is ALWAYS the weight-base (ws); A = W3 + g*1M.
// ---------------------------------------------------------------------------
template <int IS_WO>
__global__ __launch_bounds__(512, 2) void gemm256(const ushort* __restrict__ W3,
                                                  const ushort* __restrict__ lidT,
                                                  const ushort* __restrict__ camT,
                                                  void* __restrict__ outp)
{
    __shared__ __align__(16) ushort sh[65536];  // [0,64K): A dbuf; [64K,128K): B dbuf
    char* shb = (char*)sh;

    const int bid = blockIdx.x;
    int g, bm, bn;
    if (IS_WO) {
        const int sid = (bid & 7) * 32 + (bid >> 3);   // 256 % 8 == 0, bijective
        g = 3; bm = sid & 3; bn = sid >> 2;
    } else {
        const int sid = (bid & 7) * 96 + (bid >> 3);   // 768 % 8 == 0, bijective
        g = sid >> 8; const int r = sid & 255; bm = r & 3; bn = r >> 2;
    }
    const int m0  = bm * 256;
    const int b   = bn >> 5;                // 64 n-tiles, 32 per batch
    const int nn0 = (bn & 31) * 4;          // q/k remap: 4 i-values per 256-tile
    const int n0  = bn * 256;               // linear B row base
    const ushort* A  = W3 + (size_t)g * (1u << 20);
    const ushort* Bt = (g == 0) ? lidT : camT;   // IS_WO: camT param carries aoT
    const bool remap = (!IS_WO) && (g < 2);

    const int tid = threadIdx.x;
    const int w   = tid >> 6;
    const int l   = tid & 63;
    const int wr  = w >> 2;       // 0..1  M half
    const int wc  = w & 3;        // 0..3  N quarter
    const int hi  = l >> 4;
    const int fr  = l & 15;

    // stage one 16KB half-tile (A or B) of K-tile kt into buffer buf.
    // dest linear; source chunk pre-swizzled (chunk ^ row&7) -> LDS holds
    // row r's global chunk kk at slot kk^(r&7)  (involution; read same XOR).
    auto stageA = [&](int buf, int kt, int half) {
        const int k0 = kt * 64;
        #pragma unroll
        for (int ld = 0; ld < 2; ++ld) {
            const int c  = w * 2 + ld;                 // chunk 0..15 (8 rows each)
            const int rt = half * 128 + c * 8 + (l >> 3);
            const int kc = ((l & 7) ^ (rt & 7)) << 3;
            gload16(A + (size_t)(m0 + rt) * CH + k0 + kc,
                    &shb[buf * 32768 + half * 16384 + c * 1024]);
        }
    };
    auto stageB = [&](int buf, int kt, int half) {
        const int k0 = kt * 64;
        #pragma unroll
        for (int ld = 0; ld < 2; ++ld) {
            const int c  = w * 2 + ld;
            const int rt = half * 128 + c * 8 + (l >> 3);
            const int kc = ((l & 7) ^ (rt & 7)) << 3;
            size_t brow;
            if (remap) brow = (size_t)b * PPB + (size_t)(rt & 63) * 128 + nn0 + (rt >> 6);
            else       brow = (size_t)(n0 + rt);
            gload16(Bt + brow * CH + k0 + kc,
                    &shb[65536 + buf * 32768 + half * 16384 + c * 1024]);
        }
    };

    f32x4 acc[8][4];
    #pragma unroll
    for (int i = 0; i < 8; ++i)
        #pragma unroll
        for (int j = 0; j < 4; ++j) acc[i][j] = (f32x4)(0.0f);

    // prologue: tile 0, all 4 halves (8 vmem instructions)
    stageA(0, 0, 0); stageA(0, 0, 1); stageB(0, 0, 0); stageB(0, 0, 1);

    for (int kt = 0; kt < 16; ++kt) {
        const int buf = kt & 1, nxt = buf ^ 1;
        // issue first half of next tile BEFORE the wait so the counted vmcnt
        // leaves it in flight across the barrier (T4: never drain to 0 mid-loop)
        if (kt < 15) {
            stageA(nxt, kt + 1, 0);
            __builtin_amdgcn_sched_barrier(0);
            asm volatile("s_waitcnt vmcnt(2)" ::: "memory");  // tile kt resident
        } else {
            __builtin_amdgcn_sched_barrier(0);
            asm volatile("s_waitcnt vmcnt(0)" ::: "memory");
        }
        __builtin_amdgcn_s_barrier();
        __builtin_amdgcn_sched_barrier(0);
        const int Ab = buf * 32768, Bb = 65536 + buf * 32768;

        #pragma unroll
        for (int q = 0; q < 4; ++q) {                  // quadrant phases
            const int mh = q >> 1, nh = q & 1;
            if (kt < 15) {                             // interleaved prefetch
                if (q == 1) stageA(nxt, kt + 1, 1);
                else if (q == 2) stageB(nxt, kt + 1, 0);
                else if (q == 3) stageB(nxt, kt + 1, 1);
            }
            short8 aq[4][2], bq[2][2];
            #pragma unroll
            for (int fm = 0; fm < 4; ++fm) {
                const int row = wr * 128 + (mh * 4 + fm) * 16 + fr;
                #pragma unroll
                for (int kk = 0; kk < 2; ++kk)
                    aq[fm][kk] = *(const short8*)&shb[Ab + row * 128 +
                        ((((kk << 2) + hi) ^ (row & 7)) << 4)];
            }
            #pragma unroll
            for (int fn = 0; fn < 2; ++fn) {
                const int row = wc * 64 + (nh * 2 + fn) * 16 + fr;
                #pragma unroll
                for (int kk = 0; kk < 2; ++kk)
                    bq[fn][kk] = *(const short8*)&shb[Bb + row * 128 +
                        ((((kk << 2) + hi) ^ (row & 7)) << 4)];
            }
            __builtin_amdgcn_s_setprio(1);
            #pragma unroll
            for (int fm = 0; fm < 4; ++fm)
                #pragma unroll
                for (int fn = 0; fn < 2; ++fn)
                    #pragma unroll
                    for (int kk = 0; kk < 2; ++kk)
                        acc[mh * 4 + fm][nh * 2 + fn] =
                            __builtin_amdgcn_mfma_f32_16x16x32_bf16(
                                aq[fm][kk], bq[fn][kk],
                                acc[mh * 4 + fm][nh * 2 + fn], 0, 0, 0);
            __builtin_amdgcn_s_setprio(0);
        }
        // my ds_reads complete before signaling; end-of-tile barrier makes
        // buf safe for tile kt+2's stages (WAR).
        __builtin_amdgcn_sched_barrier(0);
        asm volatile("s_waitcnt lgkmcnt(0)" ::: "memory");
        __builtin_amdgcn_sched_barrier(0);
        __builtin_amdgcn_s_barrier();
    }

    // epilogue: C/D col=fr, row=hi*4+r (m89-verified)
    #pragma unroll
    for (int fm = 0; fm < 8; ++fm)
        #pragma unroll
        for (int fn = 0; fn < 4; ++fn)
            #pragma unroll
            for (int r = 0; r < 4; ++r) {
                const int m = m0 + wr * 128 + fm * 16 + hi * 4 + r;
                const int s = (bn & 31) * 256 + wc * 64 + fn * 16 + fr;
                const float vv = acc[fm][fn][r];
                const size_t off = (size_t)b * CH * PPB + (size_t)m * PPB + s;
                if (IS_WO) {
                    ((float*)outp)[off] = 0.5f * vv * (1.0f + erff(vv * 0.70710678118654752f));
                } else {
                    ((ushort*)outp)[(size_t)g * ((size_t)16 << 20) + off] = f2bf(vv);
                }
            }
}

// ---------------------------------------------------------------------------
// MFMA attention, one (b,h) per block, 4 waves (unchanged from rounds 3/4).
// ---------------------------------------------------------------------------
__global__ __launch_bounds__(256, 2) void attn_mfma(const ushort* __restrict__ qt,
                                                    const ushort* __restrict__ kt,
                                                    const ushort* __restrict__ vn,
                                                    ushort* __restrict__ ot)
{
    __shared__ ushort Qs[8192];
    __shared__ ushort Ks[8192];
    __shared__ ushort Vs[8192];
    __shared__ ushort Ps[16384];

    const int bh  = blockIdx.x;
    const int tid = threadIdx.x;
    const int w   = tid >> 6;
    const int l   = tid & 63;
    const int hi  = l >> 4;
    const int fr  = l & 15;
    const size_t base = (size_t)bh * 8192;

    {
        const int lr = l >> 3, lb = l & 7;
        const int vr = l >> 4, vbk = l & 15;
        #pragma unroll
        for (int q = 0; q < 4; ++q) {
            const int ch = w * 4 + q;
            const int i  = ch * 8 + lr;
            gload16(qt + base + i * 64 + ((lb ^ (i & 7)) << 3), &Qs[ch * 512]);
            gload16(kt + base + i * 64 + ((lb ^ (i & 7)) << 3), &Ks[ch * 512]);
            const int d  = ch * 4 + vr;
            gload16(vn + base + d * 128 + ((vbk ^ (d & 15)) << 3), &Vs[ch * 512]);
        }
    }
    __syncthreads();

    const int i0w = w * 32;
    f32x4 accS[2][8];
    #pragma unroll
    for (int a = 0; a < 2; ++a)
        #pragma unroll
        for (int bjj = 0; bjj < 8; ++bjj) accS[a][bjj] = (f32x4)(0.0f);

    #pragma unroll
    for (int kk = 0; kk < 2; ++kk) {
        const int blk = kk * 4 + hi;
        short8 aq[2];
        #pragma unroll
        for (int fm = 0; fm < 2; ++fm) {
            const int i = i0w + fm * 16 + fr;
            aq[fm] = *(const short8*)&Qs[i * 64 + ((blk ^ (i & 7)) << 3)];
        }
        #pragma unroll
        for (int fn = 0; fn < 8; ++fn) {
            const int j = fn * 16 + fr;
            const short8 bk = *(const short8*)&Ks[j * 64 + ((blk ^ (j & 7)) << 3)];
            #pragma unroll
            for (int fm = 0; fm < 2; ++fm)
                accS[fm][fn] = __builtin_amdgcn_mfma_f32_16x16x32_bf16(
                    aq[fm], bk, accS[fm][fn], 0, 0, 0);
        }
    }

    const float CS = 0.125f * 1.44269504088896341f;
    #pragma unroll
    for (int fm = 0; fm < 2; ++fm) {
        #pragma unroll
        for (int r = 0; r < 4; ++r) {
            float mx = accS[fm][0][r];
            #pragma unroll
            for (int fn = 1; fn < 8; ++fn) mx = fmaxf(mx, accS[fm][fn][r]);
            #pragma unroll
            for (int msk = 1; msk <= 8; msk <<= 1) mx = fmaxf(mx, __shfl_xor(mx, msk, 64));
            float e[8], sum = 0.f;
            #pragma unroll
            for (int fn = 0; fn < 8; ++fn) {
                e[fn] = exp2f((accS[fm][fn][r] - mx) * CS);
                sum += e[fn];
            }
            #pragma unroll
            for (int msk = 1; msk <= 8; msk <<= 1) sum += __shfl_xor(sum, msk, 64);
            const float is = 1.0f / sum;
            const int i = i0w + fm * 16 + hi * 4 + r;
            #pragma unroll
            for (int fn = 0; fn < 8; ++fn) {
                const int j = fn * 16 + fr;
                Ps[i * 128 + (((j >> 3) ^ (i & 15)) << 3) + (j & 7)] = f2bf(e[fn] * is);
            }
        }
    }

    f32x4 accO[2][4];
    #pragma unroll
    for (int a = 0; a < 2; ++a)
        #pragma unroll
        for (int bjj = 0; bjj < 4; ++bjj) accO[a][bjj] = (f32x4)(0.0f);

    #pragma unroll
    for (int ks2 = 0; ks2 < 4; ++ks2) {
        const int blk = ks2 * 4 + hi;
        short8 ap[2];
        #pragma unroll
        for (int fm = 0; fm < 2; ++fm) {
            const int i = i0w + fm * 16 + fr;
            ap[fm] = *(const short8*)&Ps[i * 128 + ((blk ^ (i & 15)) << 3)];
        }
        #pragma unroll
        for (int fn2 = 0; fn2 < 4; ++fn2) {
            const int d = fn2 * 16 + fr;
            const short8 bv = *(const short8*)&Vs[d * 128 + ((blk ^ (d & 15)) << 3)];
            #pragma unroll
            for (int fm = 0; fm < 2; ++fm)
                accO[fm][fn2] = __builtin_amdgcn_mfma_f32_16x16x32_bf16(
                    ap[fm], bv, accO[fm][fn2], 0, 0, 0);
        }
    }

    #pragma unroll
    for (int fm = 0; fm < 2; ++fm)
        #pragma unroll
        for (int fn2 = 0; fn2 < 4; ++fn2)
            #pragma unroll
            for (int r = 0; r < 4; ++r) {
                const int i = i0w + fm * 16 + hi * 4 + r;
                const int d = fn2 * 16 + fr;
                ot[base + i * 64 + d] = f2bf(accO[fm][fn2][r]);
            }
}

// ---------------------------------------------------------------------------
extern "C" void kernel_launch(void* const* d_in, const int* in_sizes, int n_in,
                              void* d_out, int out_size, void* d_ws, size_t ws_size,
                              hipStream_t stream)
{
    const float* lidar = (const float*)d_in[0];
    const float* cam   = (const float*)d_in[1];
    const float* Wq    = (const float*)d_in[2];
    const float* Wk    = (const float*)d_in[3];
    const float* Wv    = (const float*)d_in[4];
    const float* Wo    = (const float*)d_in[5];

    ushort* ws = (ushort*)d_ws;
    const size_t M1 = (size_t)1 << 20;
    const size_t TT = (size_t)16 << 20;
    ushort* lidT = ws + 4 * M1;
    ushort* camT = lidT + TT;
    ushort* qb   = camT + TT;   // q_t [b][c][i][d]; attn overwrites with O_t
    ushort* aoT  = lidT;        // reuse (lidT dead after q GEMM)

    prep<<<dim3(10240), dim3(256), 0, stream>>>(lidar, cam, Wq, Wk, Wv, Wo, ws, lidT, camT);

    gemm256<0><<<dim3(768), dim3(512), 0, stream>>>(ws, lidT, camT, qb);

    attn_mfma<<<dim3(2048), dim3(256), 0, stream>>>(qb, qb + TT, qb + 2 * TT, qb);

    transpose_ao<<<dim3(128, 16, 2), dim3(256), 0, stream>>>(qb, aoT);

    // W3 = ws (weight base): g=3 selects Wo at ws+3M.  (r5 bug: passed Wob here,
    // double-offsetting A to ws+6M = lidT garbage.)
    gemm256<1><<<dim3(256), dim3(512), 0, stream>>>(ws, aoT, aoT, (float*)d_out);
}

// Round 7
// 259.938 us; speedup vs baseline: 7.2571x; 1.0323x over previous
//
#include <hip/hip_runtime.h>
#include <math.h>

#define CH  1024
#define PPB 8192            // positions per batch (D*N = 64*128)

typedef __attribute__((ext_vector_type(8))) short short8;
typedef __attribute__((ext_vector_type(4))) float f32x4;

__device__ __forceinline__ ushort f2bf(float x) {
    uint u = __float_as_uint(x);
    return (ushort)((u + 0x7FFFu + ((u >> 16) & 1u)) >> 16);   // RNE
}
__device__ __forceinline__ float bf2f(ushort u) {
    return __uint_as_float(((uint)u) << 16);
}
__device__ __forceinline__ void gload16(const void* g, const void* l) {
    __builtin_amdgcn_global_load_lds((const __attribute__((address_space(1))) void*)g,
                                     (__attribute__((address_space(3))) void*)l, 16, 0, 0);
}

// ---------------------------------------------------------------------------
// Fused prep: [0,2048) weight fp32->bf16; [2048,6144) lidar transpose;
// [6144,10240) cam transpose.  transpose: in[b][c][p] f32 -> out[b][p][c] bf16
// ---------------------------------------------------------------------------
__global__ __launch_bounds__(256) void prep(const float* __restrict__ lidar,
                                            const float* __restrict__ cam,
                                            const float* __restrict__ Wq,
                                            const float* __restrict__ Wk,
                                            const float* __restrict__ Wv,
                                            const float* __restrict__ Wo,
                                            ushort* __restrict__ wdst,
                                            ushort* __restrict__ lidT,
                                            ushort* __restrict__ camT)
{
    __shared__ float T[64][65];
    const int blk = blockIdx.x;
    const int tid = threadIdx.x;

    if (blk < 2048) {      // ---- weight convert: 4 x 1M elems ----
        const int y = blk >> 9;
        const int x = blk & 511;
        const float* w = (y == 0) ? Wq : (y == 1) ? Wk : (y == 2) ? Wv : Wo;
        ushort* o = wdst + (size_t)y * (1u << 20);
        const int idx = (x * 256 + tid) * 8;
        const float4 v0 = *(const float4*)(w + idx);
        const float4 v1 = *(const float4*)(w + idx + 4);
        ushort4 o0, o1;
        o0.x = f2bf(v0.x); o0.y = f2bf(v0.y); o0.z = f2bf(v0.z); o0.w = f2bf(v0.w);
        o1.x = f2bf(v1.x); o1.y = f2bf(v1.y); o1.z = f2bf(v1.z); o1.w = f2bf(v1.w);
        *(ushort4*)(o + idx)     = o0;
        *(ushort4*)(o + idx + 4) = o1;
        return;
    }

    // ---- transpose+convert ----
    const int t = blk - 2048;
    const bool isLid = (t < 4096);
    const int tt = isLid ? t : t - 4096;
    const float* in = isLid ? lidar : cam;
    ushort* out = isLid ? lidT : camT;

    const int p0 = (tt & 127) * 64;
    const int c0 = ((tt >> 7) & 15) * 64;
    const int b  = tt >> 11;
    const int rc = tid >> 4;            // 0..15
    const int rp = (tid & 15) * 4;      // 0..60

    #pragma unroll
    for (int pass = 0; pass < 4; ++pass) {
        const int c = pass * 16 + rc;
        const size_t base = ((size_t)(b * CH + c0 + c)) * PPB + p0 + rp;
        const float4 v = *(const float4*)(in + base);
        T[c][rp] = v.x; T[c][rp + 1] = v.y; T[c][rp + 2] = v.z; T[c][rp + 3] = v.w;
    }
    __syncthreads();
    #pragma unroll
    for (int pass = 0; pass < 4; ++pass) {
        const int p = pass * 16 + rc;
        ushort4 o;
        o.x = f2bf(T[rp + 0][p]); o.y = f2bf(T[rp + 1][p]);
        o.z = f2bf(T[rp + 2][p]); o.w = f2bf(T[rp + 3][p]);
        *(ushort4*)(out + ((size_t)(b * PPB + p0 + p)) * CH + c0 + rp) = o;
    }
}

// ---------------------------------------------------------------------------
// bf16 transpose with attn-out remap: in[b][c][s] bf16 (s=i*64+d) ->
// out[b][d*128+i][c] bf16
// ---------------------------------------------------------------------------
__global__ __launch_bounds__(256) void transpose_ao(const ushort* __restrict__ in_,
                                                    ushort* __restrict__ out)
{
    __shared__ float T[64][65];
    const int p0 = blockIdx.x * 64;
    const int c0 = blockIdx.y * 64;
    const int b  = blockIdx.z;
    const int t  = threadIdx.x;
    const int rc = t >> 4;
    const int rp = (t & 15) * 4;

    #pragma unroll
    for (int pass = 0; pass < 4; ++pass) {
        const int c = pass * 16 + rc;
        const size_t base = ((size_t)(b * CH + c0 + c)) * PPB + p0 + rp;
        const ushort4 v = *(const ushort4*)(in_ + base);
        T[c][rp]     = bf2f(v.x); T[c][rp + 1] = bf2f(v.y);
        T[c][rp + 2] = bf2f(v.z); T[c][rp + 3] = bf2f(v.w);
    }
    __syncthreads();
    #pragma unroll
    for (int pass = 0; pass < 4; ++pass) {
        const int p = pass * 16 + rc;                    // tile-local s
        const int prow = p * 128 + blockIdx.x;           // s=i*64+d -> p=d*128+i
        ushort4 o;
        o.x = f2bf(T[rp + 0][p]); o.y = f2bf(T[rp + 1][p]);
        o.z = f2bf(T[rp + 2][p]); o.w = f2bf(T[rp + 3][p]);
        *(ushort4*)(out + ((size_t)(b * PPB + prow)) * CH + c0 + rp) = o;
    }
}

// ---------------------------------------------------------------------------
// 256x256 8-phase bf16 MFMA GEMM (T2+T3+T4+T5), BK=64, 8 waves (2M x 4N),
// per-wave output 128x64. LDS 128KB = A[2][256][64] + B[2][256][64] bf16,
// XOR-swizzled (chunk ^= row&7, both-sides). Counted vmcnt (never 0 in loop).
// R7: snake quadrant order (0,0)->(0,1)->(1,1)->(1,0) with fragment reuse
// (48 -> 28 ds_read_b128 per K-tile) and kk-outer MFMA (dep distance 8).
// IS_WO=0: 768 blocks, g=0:q(lidT,remap) 1:k(camT,remap) 2:v(camT,linear),
//          bf16 out3 + g*16M.  IS_WO=1: 256 blocks, g=3, B linear, f32 gelu.
// W3 is ALWAYS the weight-base (ws); A = W3 + g*1M.
// ---------------------------------------------------------------------------
template <int IS_WO>
__global__ __launch_bounds__(512, 2) void gemm256(const ushort* __restrict__ W3,
                                                  const ushort* __restrict__ lidT,
                                                  const ushort* __restrict__ camT,
                                                  void* __restrict__ outp)
{
    __shared__ __align__(16) ushort sh[65536];  // [0,64K): A dbuf; [64K,128K): B dbuf
    char* shb = (char*)sh;

    const int bid = blockIdx.x;
    int g, bm, bn;
    if (IS_WO) {
        const int sid = (bid & 7) * 32 + (bid >> 3);   // 256 % 8 == 0, bijective
        g = 3; bm = sid & 3; bn = sid >> 2;
    } else {
        const int sid = (bid & 7) * 96 + (bid >> 3);   // 768 % 8 == 0, bijective
        g = sid >> 8; const int r = sid & 255; bm = r & 3; bn = r >> 2;
    }
    const int m0  = bm * 256;
    const int b   = bn >> 5;                // 64 n-tiles, 32 per batch
    const int nn0 = (bn & 31) * 4;          // q/k remap: 4 i-values per 256-tile
    const int n0  = bn * 256;               // linear B row base
    const ushort* A  = W3 + (size_t)g * (1u << 20);
    const ushort* Bt = (g == 0) ? lidT : camT;   // IS_WO: camT param carries aoT
    const bool remap = (!IS_WO) && (g < 2);

    const int tid = threadIdx.x;
    const int w   = tid >> 6;
    const int l   = tid & 63;
    const int wr  = w >> 2;       // 0..1  M half
    const int wc  = w & 3;        // 0..3  N quarter
    const int hi  = l >> 4;
    const int fr  = l & 15;

    // stage one 16KB half-tile (A or B) of K-tile kt into buffer buf.
    // dest linear; source chunk pre-swizzled (chunk ^ row&7) -> LDS holds
    // row r's global chunk kk at slot kk^(r&7)  (involution; read same XOR).
    auto stageA = [&](int buf, int kt, int half) {
        const int k0 = kt * 64;
        #pragma unroll
        for (int ld = 0; ld < 2; ++ld) {
            const int c  = w * 2 + ld;                 // chunk 0..15 (8 rows each)
            const int rt = half * 128 + c * 8 + (l >> 3);
            const int kc = ((l & 7) ^ (rt & 7)) << 3;
            gload16(A + (size_t)(m0 + rt) * CH + k0 + kc,
                    &shb[buf * 32768 + half * 16384 + c * 1024]);
        }
    };
    auto stageB = [&](int buf, int kt, int half) {
        const int k0 = kt * 64;
        #pragma unroll
        for (int ld = 0; ld < 2; ++ld) {
            const int c  = w * 2 + ld;
            const int rt = half * 128 + c * 8 + (l >> 3);
            const int kc = ((l & 7) ^ (rt & 7)) << 3;
            size_t brow;
            if (remap) brow = (size_t)b * PPB + (size_t)(rt & 63) * 128 + nn0 + (rt >> 6);
            else       brow = (size_t)(n0 + rt);
            gload16(Bt + brow * CH + k0 + kc,
                    &shb[65536 + buf * 32768 + half * 16384 + c * 1024]);
        }
    };

    f32x4 acc[8][4];
    #pragma unroll
    for (int i = 0; i < 8; ++i)
        #pragma unroll
        for (int j = 0; j < 4; ++j) acc[i][j] = (f32x4)(0.0f);

    // prologue: tile 0, all 4 halves (8 vmem instructions)
    stageA(0, 0, 0); stageA(0, 0, 1); stageB(0, 0, 0); stageB(0, 0, 1);

    for (int kt = 0; kt < 16; ++kt) {
        const int buf = kt & 1, nxt = buf ^ 1;
        // issue first half of next tile BEFORE the wait so the counted vmcnt
        // leaves it in flight across the barrier (T4: never drain to 0 mid-loop)
        if (kt < 15) {
            stageA(nxt, kt + 1, 0);
            __builtin_amdgcn_sched_barrier(0);
            asm volatile("s_waitcnt vmcnt(2)" ::: "memory");  // tile kt resident
        } else {
            __builtin_amdgcn_sched_barrier(0);
            asm volatile("s_waitcnt vmcnt(0)" ::: "memory");
        }
        __builtin_amdgcn_s_barrier();
        __builtin_amdgcn_sched_barrier(0);
        const int Ab = buf * 32768, Bb = 65536 + buf * 32768;

        short8 aq[4][2], bq[2][2];
        auto LDA = [&](int mh) {
            #pragma unroll
            for (int fm = 0; fm < 4; ++fm) {
                const int row = wr * 128 + (mh * 4 + fm) * 16 + fr;
                #pragma unroll
                for (int kk = 0; kk < 2; ++kk)
                    aq[fm][kk] = *(const short8*)&shb[Ab + row * 128 +
                        ((((kk << 2) + hi) ^ (row & 7)) << 4)];
            }
        };
        auto LDB = [&](int nh) {
            #pragma unroll
            for (int fn = 0; fn < 2; ++fn) {
                const int row = wc * 64 + (nh * 2 + fn) * 16 + fr;
                #pragma unroll
                for (int kk = 0; kk < 2; ++kk)
                    bq[fn][kk] = *(const short8*)&shb[Bb + row * 128 +
                        ((((kk << 2) + hi) ^ (row & 7)) << 4)];
            }
        };
        auto MF = [&](int mh, int nh) {     // kk-outer: 8 independent per kk
            __builtin_amdgcn_s_setprio(1);
            #pragma unroll
            for (int kk = 0; kk < 2; ++kk)
                #pragma unroll
                for (int fm = 0; fm < 4; ++fm)
                    #pragma unroll
                    for (int fn = 0; fn < 2; ++fn)
                        acc[mh * 4 + fm][nh * 2 + fn] =
                            __builtin_amdgcn_mfma_f32_16x16x32_bf16(
                                aq[fm][kk], bq[fn][kk],
                                acc[mh * 4 + fm][nh * 2 + fn], 0, 0, 0);
            __builtin_amdgcn_s_setprio(0);
        };

        // snake order: aq read for mh=0 (Q0,Q1), mh=1 (Q2,Q3); bq per quadrant
        LDA(0); LDB(0);              MF(0, 0);
        if (kt < 15) stageA(nxt, kt + 1, 1);
        LDB(1);                      MF(0, 1);
        if (kt < 15) stageB(nxt, kt + 1, 0);
        LDA(1);                      MF(1, 1);
        if (kt < 15) stageB(nxt, kt + 1, 1);
        LDB(0);                      MF(1, 0);

        // my ds_reads complete before signaling; end-of-tile barrier makes
        // buf safe for tile kt+2's stages (WAR).
        __builtin_amdgcn_sched_barrier(0);
        asm volatile("s_waitcnt lgkmcnt(0)" ::: "memory");
        __builtin_amdgcn_sched_barrier(0);
        __builtin_amdgcn_s_barrier();
    }

    // epilogue: C/D col=fr, row=hi*4+r (m89-verified)
    #pragma unroll
    for (int fm = 0; fm < 8; ++fm)
        #pragma unroll
        for (int fn = 0; fn < 4; ++fn)
            #pragma unroll
            for (int r = 0; r < 4; ++r) {
                const int m = m0 + wr * 128 + fm * 16 + hi * 4 + r;
                const int s = (bn & 31) * 256 + wc * 64 + fn * 16 + fr;
                const float vv = acc[fm][fn][r];
                const size_t off = (size_t)b * CH * PPB + (size_t)m * PPB + s;
                if (IS_WO) {
                    ((float*)outp)[off] = 0.5f * vv * (1.0f + erff(vv * 0.70710678118654752f));
                } else {
                    ((ushort*)outp)[(size_t)g * ((size_t)16 << 20) + off] = f2bf(vv);
                }
            }
}

// ---------------------------------------------------------------------------
// MFMA attention, one (b,h) per block, 4 waves (unchanged from rounds 3-6).
// ---------------------------------------------------------------------------
__global__ __launch_bounds__(256, 2) void attn_mfma(const ushort* __restrict__ qt,
                                                    const ushort* __restrict__ kt,
                                                    const ushort* __restrict__ vn,
                                                    ushort* __restrict__ ot)
{
    __shared__ ushort Qs[8192];
    __shared__ ushort Ks[8192];
    __shared__ ushort Vs[8192];
    __shared__ ushort Ps[16384];

    const int bh  = blockIdx.x;
    const int tid = threadIdx.x;
    const int w   = tid >> 6;
    const int l   = tid & 63;
    const int hi  = l >> 4;
    const int fr  = l & 15;
    const size_t base = (size_t)bh * 8192;

    {
        const int lr = l >> 3, lb = l & 7;
        const int vr = l >> 4, vbk = l & 15;
        #pragma unroll
        for (int q = 0; q < 4; ++q) {
            const int ch = w * 4 + q;
            const int i  = ch * 8 + lr;
            gload16(qt + base + i * 64 + ((lb ^ (i & 7)) << 3), &Qs[ch * 512]);
            gload16(kt + base + i * 64 + ((lb ^ (i & 7)) << 3), &Ks[ch * 512]);
            const int d  = ch * 4 + vr;
            gload16(vn + base + d * 128 + ((vbk ^ (d & 15)) << 3), &Vs[ch * 512]);
        }
    }
    __syncthreads();

    const int i0w = w * 32;
    f32x4 accS[2][8];
    #pragma unroll
    for (int a = 0; a < 2; ++a)
        #pragma unroll
        for (int bjj = 0; bjj < 8; ++bjj) accS[a][bjj] = (f32x4)(0.0f);

    #pragma unroll
    for (int kk = 0; kk < 2; ++kk) {
        const int blk = kk * 4 + hi;
        short8 aq[2];
        #pragma unroll
        for (int fm = 0; fm < 2; ++fm) {
            const int i = i0w + fm * 16 + fr;
            aq[fm] = *(const short8*)&Qs[i * 64 + ((blk ^ (i & 7)) << 3)];
        }
        #pragma unroll
        for (int fn = 0; fn < 8; ++fn) {
            const int j = fn * 16 + fr;
            const short8 bk = *(const short8*)&Ks[j * 64 + ((blk ^ (j & 7)) << 3)];
            #pragma unroll
            for (int fm = 0; fm < 2; ++fm)
                accS[fm][fn] = __builtin_amdgcn_mfma_f32_16x16x32_bf16(
                    aq[fm], bk, accS[fm][fn], 0, 0, 0);
        }
    }

    const float CS = 0.125f * 1.44269504088896341f;
    #pragma unroll
    for (int fm = 0; fm < 2; ++fm) {
        #pragma unroll
        for (int r = 0; r < 4; ++r) {
            float mx = accS[fm][0][r];
            #pragma unroll
            for (int fn = 1; fn < 8; ++fn) mx = fmaxf(mx, accS[fm][fn][r]);
            #pragma unroll
            for (int msk = 1; msk <= 8; msk <<= 1) mx = fmaxf(mx, __shfl_xor(mx, msk, 64));
            float e[8], sum = 0.f;
            #pragma unroll
            for (int fn = 0; fn < 8; ++fn) {
                e[fn] = exp2f((accS[fm][fn][r] - mx) * CS);
                sum += e[fn];
            }
            #pragma unroll
            for (int msk = 1; msk <= 8; msk <<= 1) sum += __shfl_xor(sum, msk, 64);
            const float is = 1.0f / sum;
            const int i = i0w + fm * 16 + hi * 4 + r;
            #pragma unroll
            for (int fn = 0; fn < 8; ++fn) {
                const int j = fn * 16 + fr;
                Ps[i * 128 + (((j >> 3) ^ (i & 15)) << 3) + (j & 7)] = f2bf(e[fn] * is);
            }
        }
    }

    f32x4 accO[2][4];
    #pragma unroll
    for (int a = 0; a < 2; ++a)
        #pragma unroll
        for (int bjj = 0; bjj < 4; ++bjj) accO[a][bjj] = (f32x4)(0.0f);

    #pragma unroll
    for (int ks2 = 0; ks2 < 4; ++ks2) {
        const int blk = ks2 * 4 + hi;
        short8 ap[2];
        #pragma unroll
        for (int fm = 0; fm < 2; ++fm) {
            const int i = i0w + fm * 16 + fr;
            ap[fm] = *(const short8*)&Ps[i * 128 + ((blk ^ (i & 15)) << 3)];
        }
        #pragma unroll
        for (int fn2 = 0; fn2 < 4; ++fn2) {
            const int d = fn2 * 16 + fr;
            const short8 bv = *(const short8*)&Vs[d * 128 + ((blk ^ (d & 15)) << 3)];
            #pragma unroll
            for (int fm = 0; fm < 2; ++fm)
                accO[fm][fn2] = __builtin_amdgcn_mfma_f32_16x16x32_bf16(
                    ap[fm], bv, accO[fm][fn2], 0, 0, 0);
        }
    }

    #pragma unroll
    for (int fm = 0; fm < 2; ++fm)
        #pragma unroll
        for (int fn2 = 0; fn2 < 4; ++fn2)
            #pragma unroll
            for (int r = 0; r < 4; ++r) {
                const int i = i0w + fm * 16 + hi * 4 + r;
                const int d = fn2 * 16 + fr;
                ot[base + i * 64 + d] = f2bf(accO[fm][fn2][r]);
            }
}

// ---------------------------------------------------------------------------
extern "C" void kernel_launch(void* const* d_in, const int* in_sizes, int n_in,
                              void* d_out, int out_size, void* d_ws, size_t ws_size,
                              hipStream_t stream)
{
    const float* lidar = (const float*)d_in[0];
    const float* cam   = (const float*)d_in[1];
    const float* Wq    = (const float*)d_in[2];
    const float* Wk    = (const float*)d_in[3];
    const float* Wv    = (const float*)d_in[4];
    const float* Wo    = (const float*)d_in[5];

    ushort* ws = (ushort*)d_ws;
    const size_t M1 = (size_t)1 << 20;
    const size_t TT = (size_t)16 << 20;
    ushort* lidT = ws + 4 * M1;
    ushort* camT = lidT + TT;
    ushort* qb   = camT + TT;   // q_t [b][c][i][d]; attn overwrites with O_t
    ushort* aoT  = lidT;        // reuse (lidT dead after q GEMM)

    prep<<<dim3(10240), dim3(256), 0, stream>>>(lidar, cam, Wq, Wk, Wv, Wo, ws, lidT, camT);

    gemm256<0><<<dim3(768), dim3(512), 0, stream>>>(ws, lidT, camT, qb);

    attn_mfma<<<dim3(2048), dim3(256), 0, stream>>>(qb, qb + TT, qb + 2 * TT, qb);

    transpose_ao<<<dim3(128, 16, 2), dim3(256), 0, stream>>>(qb, aoT);

    gemm256<1><<<dim3(256), dim3(512), 0, stream>>>(ws, aoT, aoT, (float*)d_out);
}